// Round 5
// baseline (1133.066 us; speedup 1.0000x reference)
//
#include <hip/hip_runtime.h>
#include <hip/hip_bf16.h>
#include <math.h>

// ---------------- problem dims (fixed by setup_inputs) ----------------
constexpr int B  = 8,  V = 64, E = 512, NS = 32;
constexpr int L  = 4,  H = 8,  D = 64,  M  = 1024, R = 128;
constexpr int HD = H * D;            // 512
constexpr int ROWS  = B * V;         // 512 distinct transformer rows
constexpr int SROWS = ROWS * NS;     // 16384 sample rows
constexpr int KVN = 4096;            // kv output columns (keys 2048 | vals 2048)

typedef _Float16 half8 __attribute__((ext_vector_type(8)));
typedef float floatx4 __attribute__((ext_vector_type(4)));

// ---------------- threefry2x32-20 (JAX-compatible, partitionable) ----------
struct TF2 { unsigned a, b; };
__host__ __device__ constexpr unsigned rotl32(unsigned x, int d) {
  return (x << d) | (x >> (32 - d));
}
__host__ __device__ constexpr TF2 threefry(unsigned k0, unsigned k1,
                                           unsigned x0, unsigned x1) {
  unsigned ks2 = k0 ^ k1 ^ 0x1BD11BDAu;
  x0 += k0; x1 += k1;
  const int ra[4] = {13, 15, 26, 6};
  const int rb[4] = {17, 29, 16, 24};
  for (int i = 0; i < 4; i++) { x0 += x1; x1 = rotl32(x1, ra[i]); x1 ^= x0; }
  x0 += k1;  x1 += ks2 + 1u;
  for (int i = 0; i < 4; i++) { x0 += x1; x1 = rotl32(x1, rb[i]); x1 ^= x0; }
  x0 += ks2; x1 += k0 + 2u;
  for (int i = 0; i < 4; i++) { x0 += x1; x1 = rotl32(x1, ra[i]); x1 ^= x0; }
  x0 += k0;  x1 += k1 + 3u;
  for (int i = 0; i < 4; i++) { x0 += x1; x1 = rotl32(x1, rb[i]); x1 ^= x0; }
  x0 += k1;  x1 += ks2 + 4u;
  for (int i = 0; i < 4; i++) { x0 += x1; x1 = rotl32(x1, ra[i]); x1 ^= x0; }
  x0 += ks2; x1 += k0 + 5u;
  return {x0, x1};
}
__device__ __forceinline__ unsigned tf_bits32(unsigned k0, unsigned k1,
                                              unsigned j) {
  TF2 r = threefry(k0, k1, 0u, j);
  return r.a ^ r.b;
}

__device__ __forceinline__ double waveReduceAdd64(double v) {
#pragma unroll
  for (int m = 32; m; m >>= 1) v += __shfl_xor(v, m, 64);
  return v;
}

__device__ __forceinline__ void split16(float v, _Float16& h, _Float16& l) {
  h = (_Float16)v;
  l = (_Float16)((v - (float)h) * 2048.0f);
}

// ---------------- coherence helpers (agent scope, NO wbl2 fences) ----------
__device__ __forceinline__ float coh_ld(const float* p) {
  return __hip_atomic_load(p, __ATOMIC_RELAXED, __HIP_MEMORY_SCOPE_AGENT);
}
__device__ __forceinline__ void coh_st(float* p, float v) {
  __hip_atomic_store(p, v, __ATOMIC_RELAXED, __HIP_MEMORY_SCOPE_AGENT);
}
__device__ __forceinline__ unsigned long long coh_ld64(
    const unsigned long long* p) {
  return __hip_atomic_load(p, __ATOMIC_RELAXED, __HIP_MEMORY_SCOPE_AGENT);
}
__device__ __forceinline__ void coh_st64(unsigned long long* p,
                                         unsigned long long v) {
  __hip_atomic_store(p, v, __ATOMIC_RELAXED, __HIP_MEMORY_SCOPE_AGENT);
}
__device__ __forceinline__ void coh_st32(unsigned* p, unsigned v) {
  __hip_atomic_store(p, v, __ATOMIC_RELAXED, __HIP_MEMORY_SCOPE_AGENT);
}
__device__ __forceinline__ unsigned pack16(_Float16 a, _Float16 b) {
  union { _Float16 h[2]; unsigned u; } cv;
  cv.h[0] = a; cv.h[1] = b;
  return cv.u;
}

// ---------------- fence-free barrier (R3-proven memory model) --------------
// arrive: __syncthreads drains vmcnt(0) (all sc0sc1 stores at coherence
// point) before thread0's device-scope atomicAdd (executes at LLC, m20).
// wait: agent-scope relaxed spin load + s_sleep; then __syncthreads.
__device__ __forceinline__ void bar_arrive(int* b) {
  __syncthreads();
  if (threadIdx.x == 0) atomicAdd(b, 1);
}
__device__ __forceinline__ void bar_wait(int* b, int target) {
  if (threadIdx.x == 0) {
    int guard = 0;
    while (__hip_atomic_load(b, __ATOMIC_RELAXED,
                             __HIP_MEMORY_SCOPE_AGENT) < target) {
      __builtin_amdgcn_s_sleep(16);
      if (++guard > (1 << 22)) break;  // hang guard
    }
  }
  __syncthreads();
}

// ---------------- merged prep: flow split + weight transpose/split +
//                  kv bias vector + counter/barrier zero, ONE launch --------
struct WArgs {
  const float* s[7];
  _Float16* h[7];
  _Float16* l[7];
};
// 0 Wsh(512,512) 1 Wk x32 2 Wv x32 3 W1 x4 4 W2 x4 5 W3 x4 6 Wd
__global__ __launch_bounds__(256) void prep_split(
    WArgs a, const float* __restrict__ flow, const float* __restrict__ bk,
    const float* __restrict__ bv, const float* __restrict__ bsh,
    _Float16* __restrict__ fh, _Float16* __restrict__ fl,
    float* __restrict__ kvb, int* __restrict__ cnt) {
  __shared__ float tile[64][65];
  const int bid = blockIdx.x, t = threadIdx.x;
  if (bid == 2915) {  // zero election counters (1024) + barriers (32)
#pragma unroll
    for (int i = 0; i < 5; i++) {
      int idx = i * 256 + t;
      if (idx < 1088) cnt[idx] = 0;
    }
    return;
  }
  if (bid < 275) {
    if (bid < 256) {
      const int base = (bid * 256 + t) * 4;
      float4 v = *(const float4*)&flow[base];
      float x[4] = {v.x, v.y, v.z, v.w};
#pragma unroll
      for (int j = 0; j < 4; j++) {
        _Float16 h, l;
        split16(x[j], h, l);
        fh[base + j] = h;
        fl[base + j] = l;
      }
    } else {
      const int idx = (bid - 256) * 256 + t;
      if (idx < KVN + HD) {
        float bb = (idx < 2048) ? bk[idx]
                 : (idx < 4096) ? bv[idx - 2048]
                                : bsh[idx - 4096];
        kvb[idx] = bb;
      }
    }
    return;
  }
  // weight transpose + split
  const int WS_OFF[8] = {0, 64, 320, 576, 1088, 2112, 2624, 2640};
  const int WS_K[7] = {512, 512, 512, 512, 1024, 1024, 512};
  const int WS_N[7] = {512, 64, 64, 1024, 1024, 512, 128};
  int wb = bid - 275;
  int mi = 0;
  while (wb >= WS_OFF[mi + 1]) mi++;
  int tt = wb - WS_OFF[mi];
  const int K = WS_K[mi], N = WS_N[mi];
  const int ktiles = K >> 6;
  const int per = ktiles * (N >> 6);
  const int z = tt / per;
  const int rem = tt - z * per;
  const int k0 = (rem % ktiles) * 64, n0 = (rem / ktiles) * 64;
  const size_t moff = (size_t)z * K * N;
  const float* src = a.s[mi] + moff;
  _Float16* dh = a.h[mi] + moff;
  _Float16* dl = a.l[mi] + moff;
#pragma unroll
  for (int i = 0; i < 16; i++) {
    int idx = i * 256 + t, r = idx >> 6, c = idx & 63;
    tile[r][c] = src[(size_t)(k0 + r) * N + n0 + c];
  }
  __syncthreads();
#pragma unroll
  for (int i = 0; i < 16; i++) {
    int idx = i * 256 + t, n = idx >> 6, k = idx & 63;
    float v = tile[k][n];
    _Float16 h, l;
    split16(v, h, l);
    dh[(size_t)(n0 + n) * K + k0 + k] = h;
    dl[(size_t)(n0 + n) * K + k0 + k] = l;
  }
}

// ---------------- 64x64 MFMA GEMM core macro-body (R9-verified) ------------
#define GEMM64_BODY(Ah, Al, Bh, Bl, K, m0, n0, kbase, kchunk, hh, mid, lds)  \
  {                                                                          \
    const int t = threadIdx.x, lane = t & 63, wave = t >> 6;                 \
    const int KT = (kchunk) >> 5;                                            \
    const int l15w = lane & 15, quadw = lane >> 4;                           \
    const _Float16* srcs[4] = {                                              \
        (Ah) + (size_t)(m0) * (K), (Al) + (size_t)(m0) * (K),                \
        (Bh) + (size_t)(n0) * (K), (Bl) + (size_t)(n0) * (K)};               \
    const _Float16* gsrc =                                                   \
        srcs[wave] + (size_t)l15w * (K) + quadw * 8 + (kbase);               \
    auto stage = [&](int buf, int kt) {                                      \
      _Float16* base = &lds[buf * 8192 + wave * 2048];                       \
      const int koff = kt * 32;                                              \
      _Pragma("unroll") for (int f = 0; f < 4; f++)                          \
          __builtin_amdgcn_global_load_lds(                                  \
              gsrc + (size_t)(f * 16) * (K) + koff, base + f * 512, 16, 0,   \
              0);                                                            \
    };                                                                       \
    const int wm = wave >> 1, wn = wave & 1;                                 \
    stage(0, 0);                                                             \
    __syncthreads();                                                         \
    for (int kt = 0; kt < KT; kt++) {                                        \
      if (kt + 1 < KT) stage((kt + 1) & 1, kt + 1);                          \
      const int bofs = (kt & 1) * 8192;                                      \
      half8 a_h[2], a_l[2], b_h[2], b_l[2];                                  \
      _Pragma("unroll") for (int i = 0; i < 2; i++) {                        \
        const int af = (wm * 2 + i) * 512 + lane * 8;                        \
        const int bf = (wn * 2 + i) * 512 + lane * 8;                        \
        a_h[i] = *(const half8*)&lds[bofs + af];                             \
        a_l[i] = *(const half8*)&lds[bofs + 2048 + af];                      \
        b_h[i] = *(const half8*)&lds[bofs + 4096 + bf];                      \
        b_l[i] = *(const half8*)&lds[bofs + 6144 + bf];                      \
      }                                                                      \
      _Pragma("unroll") for (int i = 0; i < 2; i++)                          \
          _Pragma("unroll") for (int j = 0; j < 2; j++) {                    \
        hh[i][j] = __builtin_amdgcn_mfma_f32_16x16x32_f16(a_h[i], b_h[j],    \
                                                          hh[i][j], 0, 0, 0);\
        mid[i][j] = __builtin_amdgcn_mfma_f32_16x16x32_f16(                  \
            a_h[i], b_l[j], mid[i][j], 0, 0, 0);                             \
        mid[i][j] = __builtin_amdgcn_mfma_f32_16x16x32_f16(                  \
            a_l[i], b_h[j], mid[i][j], 0, 0, 0);                             \
      }                                                                      \
      __syncthreads();                                                       \
    }                                                                        \
  }

// COH-A variant: A-operand (waves 0,1) comes from an intra-kernel coherent
// buffer -> manual agent-scope u64 loads + LDS writes (same dest layout as
// global_load_lds: uniform base + lane*16B). B (weights) stays cached.
#define GEMM64_BODY_COHA(Ah, Al, Bh, Bl, K, m0, n0, kbase, kchunk, hh, mid, \
                         lds)                                                \
  {                                                                          \
    const int t = threadIdx.x, lane = t & 63, wave = t >> 6;                 \
    const int KT = (kchunk) >> 5;                                            \
    const int l15w = lane & 15, quadw = lane >> 4;                           \
    const _Float16* srcs[4] = {                                              \
        (Ah) + (size_t)(m0) * (K), (Al) + (size_t)(m0) * (K),                \
        (Bh) + (size_t)(n0) * (K), (Bl) + (size_t)(n0) * (K)};               \
    const _Float16* gsrc =                                                   \
        srcs[wave] + (size_t)l15w * (K) + quadw * 8 + (kbase);               \
    auto stage = [&](int buf, int kt) {                                      \
      _Float16* base = &lds[buf * 8192 + wave * 2048];                       \
      const int koff = kt * 32;                                              \
      if (wave < 2) {                                                        \
        _Pragma("unroll") for (int f = 0; f < 4; f++) {                      \
          const unsigned long long* gp =                                     \
              (const unsigned long long*)(gsrc + (size_t)(f * 16) * (K) +    \
                                          koff);                             \
          unsigned long long a0 = coh_ld64(gp);                              \
          unsigned long long a1 = coh_ld64(gp + 1);                          \
          unsigned long long* lp =                                           \
              (unsigned long long*)(base + f * 512 + lane * 8);              \
          lp[0] = a0;                                                        \
          lp[1] = a1;                                                        \
        }                                                                    \
      } else {                                                               \
        _Pragma("unroll") for (int f = 0; f < 4; f++)                        \
            __builtin_amdgcn_global_load_lds(                                \
                gsrc + (size_t)(f * 16) * (K) + koff, base + f * 512, 16, 0, \
                0);                                                          \
      }                                                                      \
    };                                                                       \
    const int wm = wave >> 1, wn = wave & 1;                                 \
    stage(0, 0);                                                             \
    __syncthreads();                                                         \
    for (int kt = 0; kt < KT; kt++) {                                        \
      if (kt + 1 < KT) stage((kt + 1) & 1, kt + 1);                          \
      const int bofs = (kt & 1) * 8192;                                      \
      half8 a_h[2], a_l[2], b_h[2], b_l[2];                                  \
      _Pragma("unroll") for (int i = 0; i < 2; i++) {                        \
        const int af = (wm * 2 + i) * 512 + lane * 8;                        \
        const int bf = (wn * 2 + i) * 512 + lane * 8;                        \
        a_h[i] = *(const half8*)&lds[bofs + af];                             \
        a_l[i] = *(const half8*)&lds[bofs + 2048 + af];                      \
        b_h[i] = *(const half8*)&lds[bofs + 4096 + bf];                      \
        b_l[i] = *(const half8*)&lds[bofs + 6144 + bf];                      \
      }                                                                      \
      _Pragma("unroll") for (int i = 0; i < 2; i++)                          \
          _Pragma("unroll") for (int j = 0; j < 2; j++) {                    \
        hh[i][j] = __builtin_amdgcn_mfma_f32_16x16x32_f16(a_h[i], b_h[j],    \
                                                          hh[i][j], 0, 0, 0);\
        mid[i][j] = __builtin_amdgcn_mfma_f32_16x16x32_f16(                  \
            a_h[i], b_l[j], mid[i][j], 0, 0, 0);                             \
        mid[i][j] = __builtin_amdgcn_mfma_f32_16x16x32_f16(                  \
            a_l[i], b_h[j], mid[i][j], 0, 0, 0);                             \
      }                                                                      \
      __syncthreads();                                                       \
    }                                                                        \
  }

#define GEMM_ACC_INIT(hh, mid)                                               \
  floatx4 hh[2][2], mid[2][2];                                               \
  _Pragma("unroll") for (int i = 0; i < 2; i++)                              \
      _Pragma("unroll") for (int j = 0; j < 2; j++) {                        \
    hh[i][j] = (floatx4){0.f, 0.f, 0.f, 0.f};                                \
    mid[i][j] = (floatx4){0.f, 0.f, 0.f, 0.f};                               \
  }

#define PARTIAL_EPI(Pz, Ndim, m0, n0, hh, mid)                               \
  {                                                                          \
    const int t = threadIdx.x, lane = t & 63, wave = t >> 6;                 \
    const int wm = wave >> 1, wn = wave & 1, quad = lane >> 4,               \
              l15 = lane & 15;                                               \
    _Pragma("unroll") for (int i = 0; i < 2; i++)                            \
        _Pragma("unroll") for (int j = 0; j < 2; j++)                        \
            _Pragma("unroll") for (int r = 0; r < 4; r++) {                  \
      float v = hh[i][j][r] + mid[i][j][r] * (1.0f / 2048.0f);               \
      const int m = (m0) + (wm * 2 + i) * 16 + quad * 4 + r;                 \
      const int n = (n0) + (wn * 2 + j) * 16 + l15;                          \
      (Pz)[(size_t)m * (Ndim) + n] = v;                                      \
    }                                                                        \
  }

#define PARTIAL_EPI_COH(Pz, Ndim, m0, n0, hh, mid)                           \
  {                                                                          \
    const int t = threadIdx.x, lane = t & 63, wave = t >> 6;                 \
    const int wm = wave >> 1, wn = wave & 1, quad = lane >> 4,               \
              l15 = lane & 15;                                               \
    _Pragma("unroll") for (int i = 0; i < 2; i++)                            \
        _Pragma("unroll") for (int j = 0; j < 2; j++)                        \
            _Pragma("unroll") for (int r = 0; r < 4; r++) {                  \
      float v = hh[i][j][r] + mid[i][j][r] * (1.0f / 2048.0f);               \
      const int m = (m0) + (wm * 2 + i) * 16 + quad * 4 + r;                 \
      const int n = (n0) + (wn * 2 + j) * 16 + l15;                          \
      coh_st(&(Pz)[(size_t)m * (Ndim) + n], v);                              \
    }                                                                        \
  }

// ================= fallback standalone kernels (R0-verified path) ==========
__global__ __launch_bounds__(256) void gemm_kv(
    const _Float16* __restrict__ Ah, const _Float16* __restrict__ Al,
    const _Float16* __restrict__ Bh, const _Float16* __restrict__ Bl,
    const float* __restrict__ kvb, float* __restrict__ kv,
    float* __restrict__ att) {
  __shared__ __align__(16) _Float16 lds[2 * 8192];
  const int n0 = blockIdx.x * 64, m0 = blockIdx.y * 64;
  GEMM_ACC_INIT(hh, mid)
  GEMM64_BODY(Ah, Al, Bh, Bl, 512, m0, n0, 0, 512, hh, mid, lds)
  const int t = threadIdx.x, lane = t & 63, wave = t >> 6;
  const int wm = wave >> 1, wn = wave & 1, quad = lane >> 4, l15 = lane & 15;
#pragma unroll
  for (int i = 0; i < 2; i++)
#pragma unroll
    for (int j = 0; j < 2; j++)
#pragma unroll
      for (int r = 0; r < 4; r++) {
        float v = hh[i][j][r] + mid[i][j][r] * (1.0f / 2048.0f);
        const int m = m0 + (wm * 2 + i) * 16 + quad * 4 + r;
        const int n = n0 + (wn * 2 + j) * 16 + l15;
        v += kvb[n];
        if (n < KVN) kv[(size_t)m * KVN + n] = v;
        else att[(size_t)m * HD + (n - KVN)] = v;
      }
}

__global__ __launch_bounds__(256) void gemm_sp(
    const _Float16* __restrict__ Ah, const _Float16* __restrict__ Al,
    const _Float16* __restrict__ Bh, const _Float16* __restrict__ Bl,
    float* __restrict__ P, int K, int kchunk, int Ndim) {
  __shared__ __align__(16) _Float16 lds[2 * 8192];
  const int n0 = blockIdx.x * 64, m0 = blockIdx.y * 64;
  const int kbase = blockIdx.z * kchunk;
  GEMM_ACC_INIT(hh, mid)
  GEMM64_BODY(Ah, Al, Bh, Bl, K, m0, n0, kbase, kchunk, hh, mid, lds)
  float* Pz = P + (size_t)blockIdx.z * ROWS * Ndim;
  PARTIAL_EPI(Pz, Ndim, m0, n0, hh, mid)
}

__global__ __launch_bounds__(256) void epi_h(
    const float* __restrict__ P, const float* __restrict__ bias,
    _Float16* __restrict__ Oh, _Float16* __restrict__ Ol, int Ndim, int kz,
    int relu) {
  const int n = blockIdx.x * 256 + threadIdx.x;
  const int m = blockIdx.y;
  const size_t MN = (size_t)ROWS * Ndim;
  const size_t id = (size_t)m * Ndim + n;
  float v = 0.0f;
  for (int z = 0; z < kz; z++) v += P[z * MN + id];
  v += bias[n];
  if (relu) v = fmaxf(v, 0.0f);
  _Float16 h, l;
  split16(v, h, l);
  Oh[id] = h;
  Ol[id] = l;
}

__global__ __launch_bounds__(256) void gemm_dist(
    const _Float16* __restrict__ Ah, const _Float16* __restrict__ Al,
    const _Float16* __restrict__ Bh, const _Float16* __restrict__ Bl,
    const float* __restrict__ bd, float* __restrict__ logits) {
  __shared__ __align__(16) _Float16 lds[2 * 8192];
  const int n0 = blockIdx.x * 64, m0 = blockIdx.y * 64;
  GEMM_ACC_INIT(hh, mid)
  GEMM64_BODY(Ah, Al, Bh, Bl, 512, m0, n0, 0, 512, hh, mid, lds)
  const int t = threadIdx.x, lane = t & 63, wave = t >> 6;
  const int wm = wave >> 1, wn = wave & 1, quad = lane >> 4, l15 = lane & 15;
#pragma unroll
  for (int i = 0; i < 2; i++)
#pragma unroll
    for (int j = 0; j < 2; j++)
#pragma unroll
      for (int r = 0; r < 4; r++) {
        float v = hh[i][j][r] + mid[i][j][r] * (1.0f / 2048.0f);
        const int m = m0 + (wm * 2 + i) * 16 + quad * 4 + r;
        const int n = n0 + (wn * 2 + j) * 16 + l15;
        logits[(size_t)m * R + n] = v + bd[n];
      }
}

__device__ __forceinline__ void attn_core(
    float* __restrict__ att, _Float16* __restrict__ att_h,
    _Float16* __restrict__ att_l, const float* __restrict__ kv,
    const float* __restrict__ g, const float* __restrict__ bb, int l, int row,
    float q0, float q1) {
  __shared__ float q[HD];
  __shared__ float sp[HD];
  __shared__ double rb[8];
  const int t = threadIdx.x;
  const int b_ = row >> 6;
  q[t] = q0;
  q[t + 256] = q1;
  __syncthreads();
#pragma unroll
  for (int rep = 0; rep < 2; rep++) {
    int idx = t + rep * 256;
    int h = idx >> 6, w = idx & 63;
    const float* kp = kv + (size_t)(b_ * 64 + w) * KVN + (l * 8 + h) * 64;
    const float* qp = q + h * D;
    double s = 0.0;
#pragma unroll 8
    for (int d = 0; d < 64; d++) s += (double)qp[d] * (double)kp[d];
    sp[idx] = (float)s * 0.125f;
  }
  __syncthreads();
  {
    int h = t >> 5, w0 = t & 31;
    float s0 = sp[h * 64 + w0], s1 = sp[h * 64 + w0 + 32];
    float mx = fmaxf(s0, s1);
#pragma unroll
    for (int m = 16; m; m >>= 1) mx = fmaxf(mx, __shfl_xor(mx, m, 32));
    float e0 = expf(s0 - mx), e1 = expf(s1 - mx);
    double sm = (double)e0 + (double)e1;
#pragma unroll
    for (int m = 16; m; m >>= 1) sm += __shfl_xor(sm, m, 32);
    sp[h * 64 + w0]      = (float)((double)e0 / sm);
    sp[h * 64 + w0 + 32] = (float)((double)e1 / sm);
  }
  __syncthreads();
  float x[2];
#pragma unroll
  for (int rep = 0; rep < 2; rep++) {
    int idx = t + rep * 256;
    int h = idx >> 6, d = idx & 63;
    const float* vp =
        kv + (size_t)(b_ * 64) * KVN + 2048 + (l * 8 + h) * 64 + d;
    const float* pp = sp + h * 64;
    double acc = 0.0;
#pragma unroll 8
    for (int w = 0; w < 64; w++)
      acc += (double)pp[w] * (double)vp[(size_t)w * KVN];
    x[rep] = q[idx] + (float)acc;
  }
  double s1 = (double)x[0] + (double)x[1];
  double s2 = (double)x[0] * (double)x[0] + (double)x[1] * (double)x[1];
  s1 = waveReduceAdd64(s1);
  s2 = waveReduceAdd64(s2);
  const int wid = t >> 6, lane = t & 63;
  if (lane == 0) { rb[wid] = s1; rb[4 + wid] = s2; }
  __syncthreads();
  double S1 = rb[0] + rb[1] + rb[2] + rb[3];
  double S2 = rb[4] + rb[5] + rb[6] + rb[7];
  double mean = S1 / (double)HD;
  double var  = S2 / (double)HD - mean * mean;
  double inv  = 1.0 / sqrt(var + (double)1e-5f);
  float y0 =
      (float)(((double)x[0] - mean) * inv * (double)g[t] + (double)bb[t]);
  float y1 = (float)(((double)x[1] - mean) * inv * (double)g[t + 256] +
                     (double)bb[t + 256]);
  att[row * HD + t] = y0;
  att[row * HD + 256 + t] = y1;
  _Float16 h0, l0, h1v, l1v;
  split16(y0, h0, l0);
  split16(y1, h1v, l1v);
  att_h[row * HD + t] = h0;
  att_l[row * HD + t] = l0;
  att_h[row * HD + 256 + t] = h1v;
  att_l[row * HD + 256 + t] = l1v;
}

__global__ __launch_bounds__(256) void attn_kernel(
    float* __restrict__ att, _Float16* __restrict__ att_h,
    _Float16* __restrict__ att_l, const float* __restrict__ kv,
    const float* __restrict__ g, const float* __restrict__ bb, int l) {
  const int t = threadIdx.x, row = blockIdx.x;
  float q0 = att[row * HD + t];
  float q1 = att[row * HD + 256 + t];
  attn_core(att, att_h, att_l, kv, g, bb, l, row, q0, q1);
}

__global__ __launch_bounds__(256) void epi_ln_attn(
    float* __restrict__ att, _Float16* __restrict__ att_h,
    _Float16* __restrict__ att_l, const float* __restrict__ P,
    const float* __restrict__ b3, const float* __restrict__ g2,
    const float* __restrict__ bb2, const float* __restrict__ kv,
    const float* __restrict__ g1, const float* __restrict__ bb1, int next_l,
    int kz) {
  __shared__ double rb[8];
  const int t = threadIdx.x, row = blockIdx.x;
  const size_t MN = (size_t)ROWS * HD;
  const size_t id0 = (size_t)row * HD + t;
  float h0 = 0.0f, h1s = 0.0f;
  for (int z = 0; z < kz; z++) {
    h0 += P[z * MN + id0];
    h1s += P[z * MN + id0 + 256];
  }
  h0 += b3[t];
  h1s += b3[t + 256];
  float x0 = att[id0] + h0;
  float x1 = att[id0 + 256] + h1s;
  double s1 = (double)x0 + (double)x1;
  double s2 = (double)x0 * (double)x0 + (double)x1 * (double)x1;
  s1 = waveReduceAdd64(s1);
  s2 = waveReduceAdd64(s2);
  const int wid = t >> 6, lane = t & 63;
  if (lane == 0) { rb[wid] = s1; rb[4 + wid] = s2; }
  __syncthreads();
  double S1 = rb[0] + rb[1] + rb[2] + rb[3];
  double S2 = rb[4] + rb[5] + rb[6] + rb[7];
  double mean = S1 / (double)HD;
  double var  = S2 / (double)HD - mean * mean;
  double inv  = 1.0 / sqrt(var + (double)1e-5f);
  float y0 =
      (float)(((double)x0 - mean) * inv * (double)g2[t] + (double)bb2[t]);
  float y1 = (float)(((double)x1 - mean) * inv * (double)g2[t + 256] +
                     (double)bb2[t + 256]);
  if (next_l < 0) {
    att[id0] = y0;
    att[id0 + 256] = y1;
    _Float16 hh0, ll0, hh1, ll1;
    split16(y0, hh0, ll0);
    split16(y1, hh1, ll1);
    att_h[id0] = hh0;
    att_l[id0] = ll0;
    att_h[id0 + 256] = hh1;
    att_l[id0 + 256] = ll1;
  } else {
    __syncthreads();
    attn_core(att, att_h, att_l, kv, g1, bb1, next_l, row, y0, y1);
  }
}

__global__ __launch_bounds__(256) void sample_kernel(
    const float* __restrict__ logits, float* __restrict__ out) {
  constexpr TF2 KC = threefry(0u, 1u, 0u, 0u);
  constexpr TF2 KU = threefry(0u, 1u, 0u, 1u);
  const int lane = threadIdx.x & 63;
  const int wid = threadIdx.x >> 6;
  const int row = blockIdx.x * 4 + wid;
  const float* lrow = logits + (row >> 5) * R;
  float bvv = -1e30f;
  int bi = 0;
#pragma unroll
  for (int rep = 0; rep < 2; rep++) {
    int r = lane + rep * 64;
    unsigned j = (unsigned)row * (unsigned)R + (unsigned)r;
    unsigned bits = tf_bits32(KC.a, KC.b, j);
    float f = __uint_as_float((bits >> 9) | 0x3f800000u) - 1.0f;
    float u = fmaxf(f, 1.17549435e-38f);
    float gv = -logf(-logf(u));
    float v = lrow[r] + gv;
    if (v > bvv) { bvv = v; bi = r; }
  }
#pragma unroll
  for (int m = 32; m; m >>= 1) {
    float ov = __shfl_xor(bvv, m, 64);
    int oi = __shfl_xor(bi, m, 64);
    if (ov > bvv || (ov == bvv && oi < bi)) { bvv = ov; bi = oi; }
  }
  if (lane == 0) {
    unsigned ub = tf_bits32(KU.a, KU.b, (unsigned)row);
    float u = __uint_as_float((ub >> 9) | 0x3f800000u) - 1.0f;
    out[row] = ((float)bi + u) * (1.0f / 128.0f);
  }
}

// ================= mega2: ONE persistent kernel, fence-free sync ===========
struct M2 {
  float *att, *kv, *P, *logits, *out;
  const float *kvb, *b1, *b2, *b3, *ln1g, *ln1b, *ln2g, *ln2b, *bd;
  const _Float16 *flow_h, *flow_l, *BKV_h, *BKV_l;
  const _Float16 *W1_h, *W1_l, *W2_h, *W2_l, *W3_h, *W3_l, *Wd_h, *Wd_l;
  _Float16 *att_h, *att_l, *h1_h, *h1_l, *h2_h, *h2_l;
  int *cnt, *bar;
};

// attention core, COH version, thread t <-> cols (2t, 2t+1)
__device__ void attn_core2(float* att, _Float16* att_h, _Float16* att_l,
                           const float* kv, const float* g, const float* bb,
                           int l, int row, float q0, float q1) {
  __shared__ float q[HD];
  __shared__ float sp[HD];
  __shared__ double rb[8];
  const int t = threadIdx.x;
  const int b_ = row >> 6;
  q[2 * t] = q0;
  q[2 * t + 1] = q1;
  __syncthreads();
#pragma unroll
  for (int rep = 0; rep < 2; rep++) {
    int idx = t + rep * 256;
    int h = idx >> 6, w = idx & 63;
    const float* kp = kv + (size_t)(b_ * 64 + w) * KVN + (l * 8 + h) * 64;
    const float* qp = q + h * D;
    double s = 0.0;
#pragma unroll 8
    for (int dd = 0; dd < 32; dd++) {
      union { unsigned long long u; float f[2]; } kk;
      kk.u = coh_ld64((const unsigned long long*)kp + dd);
      s += (double)qp[2 * dd] * (double)kk.f[0];
      s += (double)qp[2 * dd + 1] * (double)kk.f[1];
    }
    sp[idx] = (float)s * 0.125f;
  }
  __syncthreads();
  {
    int h = t >> 5, w0 = t & 31;
    float s0 = sp[h * 64 + w0], s1 = sp[h * 64 + w0 + 32];
    float mx = fmaxf(s0, s1);
#pragma unroll
    for (int m = 16; m; m >>= 1) mx = fmaxf(mx, __shfl_xor(mx, m, 32));
    float e0 = expf(s0 - mx), e1 = expf(s1 - mx);
    double sm = (double)e0 + (double)e1;
#pragma unroll
    for (int m = 16; m; m >>= 1) sm += __shfl_xor(sm, m, 32);
    sp[h * 64 + w0]      = (float)((double)e0 / sm);
    sp[h * 64 + w0 + 32] = (float)((double)e1 / sm);
  }
  __syncthreads();
  float x[2];
#pragma unroll
  for (int rep = 0; rep < 2; rep++) {
    int col = 2 * t + rep;
    int h = col >> 6, d = col & 63;
    const float* vp =
        kv + (size_t)(b_ * 64) * KVN + 2048 + (l * 8 + h) * 64 + d;
    const float* pp = sp + h * 64;
    double acc = 0.0;
#pragma unroll 8
    for (int w = 0; w < 64; w++)
      acc += (double)pp[w] * (double)coh_ld(vp + (size_t)w * KVN);
    x[rep] = q[col] + (float)acc;
  }
  double s1 = (double)x[0] + (double)x[1];
  double s2 = (double)x[0] * (double)x[0] + (double)x[1] * (double)x[1];
  s1 = waveReduceAdd64(s1);
  s2 = waveReduceAdd64(s2);
  const int wid = t >> 6, lane = t & 63;
  if (lane == 0) { rb[wid] = s1; rb[4 + wid] = s2; }
  __syncthreads();
  double S1 = rb[0] + rb[1] + rb[2] + rb[3];
  double S2 = rb[4] + rb[5] + rb[6] + rb[7];
  double mean = S1 / (double)HD;
  double var  = S2 / (double)HD - mean * mean;
  double inv  = 1.0 / sqrt(var + (double)1e-5f);
  float y0 = (float)(((double)x[0] - mean) * inv * (double)g[2 * t] +
                     (double)bb[2 * t]);
  float y1 = (float)(((double)x[1] - mean) * inv * (double)g[2 * t + 1] +
                     (double)bb[2 * t + 1]);
  union { unsigned long long u; float f[2]; } pr;
  pr.f[0] = y0; pr.f[1] = y1;
  coh_st64((unsigned long long*)(att + (size_t)row * HD + 2 * t), pr.u);
  _Float16 h0, l0, h1v, l1v;
  split16(y0, h0, l0);
  split16(y1, h1v, l1v);
  coh_st32((unsigned*)att_h + (size_t)row * 256 + t, pack16(h0, h1v));
  coh_st32((unsigned*)att_l + (size_t)row * 256 + t, pack16(l0, l1v));
}

__device__ void kv_job(const M2& A, int job, _Float16* lds) {
  const int n0 = (job % 72) * 64, m0 = (job / 72) * 64;
  GEMM_ACC_INIT(hh, mid)
  GEMM64_BODY(A.flow_h, A.flow_l, A.BKV_h, A.BKV_l, 512, m0, n0, 0, 512,
              hh, mid, lds)
  const int t0 = threadIdx.x, lane = t0 & 63, wave = t0 >> 6;
  const int wm = wave >> 1, wn = wave & 1, quad = lane >> 4, l15 = lane & 15;
#pragma unroll
  for (int i = 0; i < 2; i++)
#pragma unroll
    for (int j = 0; j < 2; j++)
#pragma unroll
      for (int r = 0; r < 4; r++) {
        float v = hh[i][j][r] + mid[i][j][r] * (1.0f / 2048.0f);
        const int m = m0 + (wm * 2 + i) * 16 + quad * 4 + r;
        const int n = n0 + (wn * 2 + j) * 16 + l15;
        v += A.kvb[n];
        if (n < KVN) coh_st(&A.kv[(size_t)m * KVN + n], v);
        else coh_st(&A.att[(size_t)m * HD + (n - KVN)], v);
      }
}

// split-K GEMM job + last-block fixup (bias+relu+split16, paired COH out)
template <int KZ>
__device__ void w_job(const _Float16* Ah, const _Float16* Al,
                      const _Float16* Bh, const _Float16* Bl, float* P,
                      const float* bias, _Float16* Oh, _Float16* Ol,
                      int* cnt, int* bar, int K, int kchunk, int Ndim,
                      int n0, int m0, int z, _Float16* lds) {
  __shared__ int isL;
  GEMM_ACC_INIT(hh, mid)
  GEMM64_BODY_COHA(Ah, Al, Bh, Bl, K, m0, n0, z * kchunk, kchunk, hh, mid,
                   lds)
  float* Pz = P + (size_t)z * ROWS * Ndim;
  PARTIAL_EPI_COH(Pz, Ndim, m0, n0, hh, mid)
  __syncthreads();  // vmcnt(0) drain: partials at coherence point
  const int tile = (m0 >> 6) * (Ndim >> 6) + (n0 >> 6);
  if (threadIdx.x == 0) isL = (atomicAdd(&cnt[tile], 1) == KZ - 1) ? 1 : 0;
  __syncthreads();
  if (isL) {
    const size_t MN = (size_t)ROWS * Ndim;
    unsigned* Oh2 = (unsigned*)Oh;
    unsigned* Ol2 = (unsigned*)Ol;
#pragma unroll
    for (int it = 0; it < 8; it++) {
      const int p = it * 256 + threadIdx.x;
      const int m = m0 + (p >> 5), n = n0 + ((p & 31) << 1);
      const size_t id = (size_t)m * Ndim + n;
      float v0 = 0.f, v1 = 0.f;
#pragma unroll
      for (int zz = 0; zz < KZ; zz++) {
        v0 += coh_ld(&P[zz * MN + id]);
        v1 += coh_ld(&P[zz * MN + id + 1]);
      }
      v0 = fmaxf(v0 + bias[n], 0.f);
      v1 = fmaxf(v1 + bias[n + 1], 0.f);
      _Float16 h0, l0, h1, l1;
      split16(v0, h0, l0);
      split16(v1, h1, l1);
      coh_st32(&Oh2[id >> 1], pack16(h0, h1));
      coh_st32(&Ol2[id >> 1], pack16(l0, l1));
    }
    __syncthreads();  // drain fixup stores before barrier bump
    if (threadIdx.x == 0) atomicAdd(bar, 1);
  }
}

__device__ void epi2(const M2& A, int l, int next_l, int row) {
  __shared__ double rbE[8];
  const int t = threadIdx.x;
  const size_t MN = (size_t)ROWS * HD;
  const size_t id0 = (size_t)row * HD + 2 * t;
  float h0 = 0.0f, h1s = 0.0f;
  for (int z = 0; z < 8; z++) {
    h0 += coh_ld(&A.P[z * MN + id0]);
    h1s += coh_ld(&A.P[z * MN + id0 + 1]);
  }
  h0 += A.b3[l * HD + 2 * t];
  h1s += A.b3[l * HD + 2 * t + 1];
  float x0 = coh_ld(&A.att[id0]) + h0;
  float x1 = coh_ld(&A.att[id0 + 1]) + h1s;
  double s1 = (double)x0 + (double)x1;
  double s2 = (double)x0 * (double)x0 + (double)x1 * (double)x1;
  s1 = waveReduceAdd64(s1);
  s2 = waveReduceAdd64(s2);
  const int wid = t >> 6, lane = t & 63;
  if (lane == 0) { rbE[wid] = s1; rbE[4 + wid] = s2; }
  __syncthreads();
  double S1 = rbE[0] + rbE[1] + rbE[2] + rbE[3];
  double S2 = rbE[4] + rbE[5] + rbE[6] + rbE[7];
  double mean = S1 / (double)HD;
  double var  = S2 / (double)HD - mean * mean;
  double inv  = 1.0 / sqrt(var + (double)1e-5f);
  const float* g2 = A.ln2g + l * HD;
  const float* bb2 = A.ln2b + l * HD;
  float y0 = (float)(((double)x0 - mean) * inv * (double)g2[2 * t] +
                     (double)bb2[2 * t]);
  float y1 = (float)(((double)x1 - mean) * inv * (double)g2[2 * t + 1] +
                     (double)bb2[2 * t + 1]);
  if (next_l < 0) {
    union { unsigned long long u; float f[2]; } pr;
    pr.f[0] = y0; pr.f[1] = y1;
    coh_st64((unsigned long long*)(A.att + id0), pr.u);
    _Float16 hh0, ll0, hh1, ll1;
    split16(y0, hh0, ll0);
    split16(y1, hh1, ll1);
    coh_st32((unsigned*)A.att_h + (size_t)row * 256 + t, pack16(hh0, hh1));
    coh_st32((unsigned*)A.att_l + (size_t)row * 256 + t, pack16(ll0, ll1));
  } else {
    __syncthreads();
    attn_core2(A.att, A.att_h, A.att_l, A.kv, A.ln1g + next_l * HD,
               A.ln1b + next_l * HD, next_l, row, y0, y1);
  }
}

__global__ __launch_bounds__(256, 2) void mega2(M2 A) {
  __shared__ __align__(16) _Float16 lds[2 * 8192];
  const int bid = blockIdx.x, t = threadIdx.x;
  int* bar = A.bar;

  // ---- P0: kv|shift GEMM, 576 jobs ----
  kv_job(A, bid, lds);
  if (bid < 64) kv_job(A, bid + 512, lds);
  bar_arrive(&bar[0]);
  bar_wait(&bar[0], 512);

  // ---- P1: attention layer 0 (row = bid) ----
  {
    float q0 = coh_ld(&A.att[(size_t)bid * HD + 2 * t]);
    float q1 = coh_ld(&A.att[(size_t)bid * HD + 2 * t + 1]);
    attn_core2(A.att, A.att_h, A.att_l, A.kv, A.ln1g, A.ln1b, 0, bid, q0, q1);
  }
  bar_arrive(&bar[1]);
  bar_wait(&bar[1], 512);

  // ---- transformer layers ----
  for (int l = 0; l < L; l++) {
    {  // W1: 128 tiles x kz4, kchunk 128
      const int tile = bid & 127, z = bid >> 7;
      w_job<4>(A.att_h, A.att_l, A.W1_h + (size_t)l * 524288,
               A.W1_l + (size_t)l * 524288, A.P, A.b1 + l * M, A.h1_h,
               A.h1_l, A.cnt + (l * 2) * 128, &bar[2 + l * 4], 512, 128, M,
               (tile & 15) * 64, (tile >> 4) * 64, z, lds);
    }
    bar_wait(&bar[2 + l * 4], 128);
#pragma unroll
    for (int jj = 0; jj < 2; jj++) {  // W2: 128 tiles x kz8, kchunk 128
      const int job = bid + jj * 512;
      const int tile = job & 127, z = job >> 7;
      w_job<8>(A.h1_h, A.h1_l, A.W2_h + (size_t)l * 1048576,
               A.W2_l + (size_t)l * 1048576, A.P, A.b2 + l * M, A.h2_h,
               A.h2_l, A.cnt + (l * 2 + 1) * 128, &bar[3 + l * 4], 1024, 128,
               M, (tile & 15) * 64, (tile >> 4) * 64, z, lds);
    }
    bar_wait(&bar[3 + l * 4], 128);
    {  // W3: 64 tiles x kz8, kchunk 128 -> partials only
      const int tile = bid & 63, z = bid >> 6;
      const int n0 = (tile & 7) * 64, m0 = (tile >> 3) * 64;
      GEMM_ACC_INIT(hh, mid)
      GEMM64_BODY_COHA(A.h2_h, A.h2_l, A.W3_h + (size_t)l * 524288,
                       A.W3_l + (size_t)l * 524288, 1024, m0, n0, z * 128,
                       128, hh, mid, lds)
      float* Pz = A.P + (size_t)z * ROWS * HD;
      PARTIAL_EPI_COH(Pz, HD, m0, n0, hh, mid)
    }
    bar_arrive(&bar[4 + l * 4]);
    bar_wait(&bar[4 + l * 4], 512);
    epi2(A, l, (l + 1 < L) ? (l + 1) : -1, bid);
    bar_arrive(&bar[5 + l * 4]);
    bar_wait(&bar[5 + l * 4], 512);
  }

  // ---- dist head: 16 direct tiles ----
  if (bid < 16) {
    const int n0 = (bid & 1) * 64, m0 = (bid >> 1) * 64;
    GEMM_ACC_INIT(hh, mid)
    GEMM64_BODY_COHA(A.att_h, A.att_l, A.Wd_h, A.Wd_l, 512, m0, n0, 0, 512,
                     hh, mid, lds)
    const int lane = t & 63, wave = t >> 6;
    const int wm = wave >> 1, wn = wave & 1, quad = lane >> 4,
              l15 = lane & 15;
#pragma unroll
    for (int i = 0; i < 2; i++)
#pragma unroll
      for (int j = 0; j < 2; j++)
#pragma unroll
        for (int r = 0; r < 4; r++) {
          float v = hh[i][j][r] + mid[i][j][r] * (1.0f / 2048.0f);
          const int m = m0 + (wm * 2 + i) * 16 + quad * 4 + r;
          const int n = n0 + (wn * 2 + j) * 16 + l15;
          coh_st(&A.logits[(size_t)m * R + n], v + A.bd[n]);
        }
  }
  bar_arrive(&bar[18]);
  bar_wait(&bar[18], 512);

  // ---- gumbel-argmax sampling ----
  {
    constexpr TF2 KC = threefry(0u, 1u, 0u, 0u);
    constexpr TF2 KU = threefry(0u, 1u, 0u, 1u);
    const int lane = t & 63, wid = t >> 6;
    for (int row = bid * 4 + wid; row < SROWS; row += 2048) {
      const float* lrow = A.logits + (row >> 5) * R;
      float bvv = -1e30f;
      int bi = 0;
#pragma unroll
      for (int rep = 0; rep < 2; rep++) {
        int r = lane + rep * 64;
        unsigned j = (unsigned)row * (unsigned)R + (unsigned)r;
        unsigned bits = tf_bits32(KC.a, KC.b, j);
        float f = __uint_as_float((bits >> 9) | 0x3f800000u) - 1.0f;
        float u = fmaxf(f, 1.17549435e-38f);
        float gv = -logf(-logf(u));
        float v = coh_ld(&lrow[r]) + gv;
        if (v > bvv) { bvv = v; bi = r; }
      }
#pragma unroll
      for (int m = 32; m; m >>= 1) {
        float ov = __shfl_xor(bvv, m, 64);
        int oi = __shfl_xor(bi, m, 64);
        if (ov > bvv || (ov == bvv && oi < bi)) { bvv = ov; bi = oi; }
      }
      if (lane == 0) {
        unsigned ub = tf_bits32(KU.a, KU.b, (unsigned)row);
        float u = __uint_as_float((ub >> 9) | 0x3f800000u) - 1.0f;
        A.out[row] = ((float)bi + u) * (1.0f / 128.0f);
      }
    }
  }
}

// ---------------- launcher ----------------
extern "C" void kernel_launch(void* const* d_in, const int* in_sizes, int n_in,
                              void* d_out, int out_size, void* d_ws,
                              size_t ws_size, hipStream_t stream) {
  (void)in_sizes; (void)n_in; (void)out_size; (void)ws_size;
  const float* flow = (const float*)d_in[0];
  const float* Wsh  = (const float*)d_in[1];
  const float* bsh  = (const float*)d_in[2];
  const float* Wk   = (const float*)d_in[3];
  const float* bk   = (const float*)d_in[4];
  const float* Wv   = (const float*)d_in[5];
  const float* bv   = (const float*)d_in[6];
  const float* ln1g = (const float*)d_in[7];
  const float* ln1b = (const float*)d_in[8];
  const float* W1   = (const float*)d_in[9];
  const float* b1   = (const float*)d_in[10];
  const float* W2   = (const float*)d_in[11];
  const float* b2   = (const float*)d_in[12];
  const float* W3   = (const float*)d_in[13];
  const float* b3   = (const float*)d_in[14];
  const float* ln2g = (const float*)d_in[15];
  const float* ln2b = (const float*)d_in[16];
  const float* Wd   = (const float*)d_in[17];
  const float* bd   = (const float*)d_in[18];

  // ---- workspace carve-up ----
  float* ws = (float*)d_ws;
  float* kv     = ws;                         // 512*4096 f32
  float* att    = kv + ROWS * KVN;            // 262,144
  float* logits = att + ROWS * HD;            // 65,536
  float* kvb    = logits + ROWS * R;          // 4,608
  int*   cnt    = (int*)(kvb + 4608);         // 1024 elections + 32 barriers
  float* P      = kvb + 4608 + 1088;          // partials (max 8*512*1024)
  _Float16* hp = (_Float16*)(P + 4718592);
  _Float16* flow_h = hp;            hp += 262144;
  _Float16* flow_l = hp;            hp += 262144;
  _Float16* BKV_h  = hp;            hp += 4608 * 512;  // Wk | Wv | Wsh, [n][k]
  _Float16* BKV_l  = hp;            hp += 4608 * 512;
  _Float16* W1_h   = hp;            hp += 2097152;
  _Float16* W1_l   = hp;            hp += 2097152;
  _Float16* W2_h   = hp;            hp += 4194304;
  _Float16* W2_l   = hp;            hp += 4194304;
  _Float16* W3_h   = hp;            hp += 2097152;
  _Float16* W3_l   = hp;            hp += 2097152;
  _Float16* Wd_h   = hp;            hp += 65536;
  _Float16* Wd_l   = hp;            hp += 65536;
  _Float16* att_h  = hp;            hp += 262144;
  _Float16* att_l  = hp;            hp += 262144;
  _Float16* h1_h   = hp;            hp += 524288;
  _Float16* h1_l   = hp;            hp += 524288;
  _Float16* h2_h   = hp;            hp += 524288;
  _Float16* h2_l   = hp;            hp += 524288;

  // ---- P0: merged prep + weight transpose/split + counter/barrier zero ----
  WArgs wa;
  wa.s[0] = Wsh; wa.h[0] = BKV_h + 4096 * 512; wa.l[0] = BKV_l + 4096 * 512;
  wa.s[1] = Wk;  wa.h[1] = BKV_h;              wa.l[1] = BKV_l;
  wa.s[2] = Wv;  wa.h[2] = BKV_h + 2048 * 512; wa.l[2] = BKV_l + 2048 * 512;
  wa.s[3] = W1;  wa.h[3] = W1_h;  wa.l[3] = W1_l;
  wa.s[4] = W2;  wa.h[4] = W2_h;  wa.l[4] = W2_l;
  wa.s[5] = W3;  wa.h[5] = W3_h;  wa.l[5] = W3_l;
  wa.s[6] = Wd;  wa.h[6] = Wd_h;  wa.l[6] = Wd_l;
  prep_split<<<2916, 256, 0, stream>>>(wa, flow, bk, bv, bsh, flow_h, flow_l,
                                       kvb, cnt);

  // ---- mega2: everything else, one cooperative launch (no grid.sync) ------
  M2 A;
  A.att = att; A.kv = kv; A.P = P; A.logits = logits; A.out = (float*)d_out;
  A.kvb = kvb; A.b1 = b1; A.b2 = b2; A.b3 = b3;
  A.ln1g = ln1g; A.ln1b = ln1b; A.ln2g = ln2g; A.ln2b = ln2b; A.bd = bd;
  A.flow_h = flow_h; A.flow_l = flow_l; A.BKV_h = BKV_h; A.BKV_l = BKV_l;
  A.W1_h = W1_h; A.W1_l = W1_l; A.W2_h = W2_h; A.W2_l = W2_l;
  A.W3_h = W3_h; A.W3_l = W3_l; A.Wd_h = Wd_h; A.Wd_l = Wd_l;
  A.att_h = att_h; A.att_l = att_l;
  A.h1_h = h1_h; A.h1_l = h1_l; A.h2_h = h2_h; A.h2_l = h2_l;
  A.cnt = cnt; A.bar = cnt + 1024;
  void* kargs[] = {&A};
  hipError_t ce = hipLaunchCooperativeKernel(
      reinterpret_cast<void*>(mega2), dim3(512), dim3(256), kargs, 0, stream);

  if (ce != hipSuccess) {
    // -------- fallback: verified R0 sequence (~419 us) ---------------------
    gemm_kv<<<dim3(72, 8), 256, 0, stream>>>(flow_h, flow_l, BKV_h, BKV_l,
                                             kvb, kv, att);
    attn_kernel<<<ROWS, 256, 0, stream>>>(att, att_h, att_l, kv, ln1g, ln1b,
                                          0);
    for (int l = 0; l < L; l++) {
      gemm_sp<<<dim3(16, 8, 4), 256, 0, stream>>>(
          att_h, att_l, W1_h + (size_t)l * 524288, W1_l + (size_t)l * 524288,
          P, 512, 128, M);
      epi_h<<<dim3(4, ROWS), 256, 0, stream>>>(P, b1 + l * M, h1_h, h1_l, M,
                                               4, 1);
      gemm_sp<<<dim3(16, 8, 8), 256, 0, stream>>>(
          h1_h, h1_l, W2_h + (size_t)l * 1048576, W2_l + (size_t)l * 1048576,
          P, 1024, 128, M);
      epi_h<<<dim3(4, ROWS), 256, 0, stream>>>(P, b2 + l * M, h2_h, h2_l, M,
                                               8, 1);
      gemm_sp<<<dim3(8, 8, 8), 256, 0, stream>>>(
          h2_h, h2_l, W3_h + (size_t)l * 524288, W3_l + (size_t)l * 524288, P,
          1024, 128, HD);
      const int nl = (l + 1 < L) ? (l + 1) : -1;
      epi_ln_attn<<<ROWS, 256, 0, stream>>>(
          att, att_h, att_l, P, b3 + l * HD, ln2g + l * HD, ln2b + l * HD, kv,
          ln1g + (nl < 0 ? 0 : nl) * HD, ln1b + (nl < 0 ? 0 : nl) * HD, nl,
          8);
    }
    gemm_dist<<<dim3(2, 8), 256, 0, stream>>>(att_h, att_l, Wd_h, Wd_l, bd,
                                              logits);
    sample_kernel<<<SROWS / 4, 256, 0, stream>>>(logits, (float*)d_out);
  }
}

// Round 6
// 1022.466 us; speedup vs baseline: 1.1082x; 1.1082x over previous
//
#include <hip/hip_runtime.h>
#include <hip/hip_bf16.h>
#include <math.h>

// ---------------- problem dims (fixed by setup_inputs) ----------------
constexpr int B  = 8,  V = 64, E = 512, NS = 32;
constexpr int L  = 4,  H = 8,  D = 64,  M  = 1024, R = 128;
constexpr int HD = H * D;            // 512
constexpr int ROWS  = B * V;         // 512 distinct transformer rows
constexpr int SROWS = ROWS * NS;     // 16384 sample rows
constexpr int KVN = 4096;            // kv output columns (keys 2048 | vals 2048)

constexpr int ATT_STR = ROWS * HD;   // 262144 f32 per att version
constexpr int AH_STR  = ROWS * HD;   // 262144 fp16 per att_h/l version
constexpr int H1_STR  = ROWS * M;    // 524288 fp16 per h1/h2 version

typedef _Float16 half8 __attribute__((ext_vector_type(8)));
typedef float floatx4 __attribute__((ext_vector_type(4)));

// ---------------- threefry2x32-20 (JAX-compatible, partitionable) ----------
struct TF2 { unsigned a, b; };
__host__ __device__ constexpr unsigned rotl32(unsigned x, int d) {
  return (x << d) | (x >> (32 - d));
}
__host__ __device__ constexpr TF2 threefry(unsigned k0, unsigned k1,
                                           unsigned x0, unsigned x1) {
  unsigned ks2 = k0 ^ k1 ^ 0x1BD11BDAu;
  x0 += k0; x1 += k1;
  const int ra[4] = {13, 15, 26, 6};
  const int rb[4] = {17, 29, 16, 24};
  for (int i = 0; i < 4; i++) { x0 += x1; x1 = rotl32(x1, ra[i]); x1 ^= x0; }
  x0 += k1;  x1 += ks2 + 1u;
  for (int i = 0; i < 4; i++) { x0 += x1; x1 = rotl32(x1, rb[i]); x1 ^= x0; }
  x0 += ks2; x1 += k0 + 2u;
  for (int i = 0; i < 4; i++) { x0 += x1; x1 = rotl32(x1, ra[i]); x1 ^= x0; }
  x0 += k0;  x1 += k1 + 3u;
  for (int i = 0; i < 4; i++) { x0 += x1; x1 = rotl32(x1, rb[i]); x1 ^= x0; }
  x0 += k1;  x1 += ks2 + 4u;
  for (int i = 0; i < 4; i++) { x0 += x1; x1 = rotl32(x1, ra[i]); x1 ^= x0; }
  x0 += ks2; x1 += k0 + 5u;
  return {x0, x1};
}
__device__ __forceinline__ unsigned tf_bits32(unsigned k0, unsigned k1,
                                              unsigned j) {
  TF2 r = threefry(k0, k1, 0u, j);
  return r.a ^ r.b;
}

__device__ __forceinline__ double waveReduceAdd64(double v) {
#pragma unroll
  for (int m = 32; m; m >>= 1) v += __shfl_xor(v, m, 64);
  return v;
}

__device__ __forceinline__ void split16(float v, _Float16& h, _Float16& l) {
  h = (_Float16)v;
  l = (_Float16)((v - (float)h) * 2048.0f);
}

// ---------------- coherence helpers (agent scope, NO wbl2 fences) ----------
__device__ __forceinline__ float coh_ld(const float* p) {
  return __hip_atomic_load(p, __ATOMIC_RELAXED, __HIP_MEMORY_SCOPE_AGENT);
}
__device__ __forceinline__ void coh_st(float* p, float v) {
  __hip_atomic_store(p, v, __ATOMIC_RELAXED, __HIP_MEMORY_SCOPE_AGENT);
}
__device__ __forceinline__ void coh_st64(unsigned long long* p,
                                         unsigned long long v) {
  __hip_atomic_store(p, v, __ATOMIC_RELAXED, __HIP_MEMORY_SCOPE_AGENT);
}
__device__ __forceinline__ void coh_st32(unsigned* p, unsigned v) {
  __hip_atomic_store(p, v, __ATOMIC_RELAXED, __HIP_MEMORY_SCOPE_AGENT);
}
__device__ __forceinline__ unsigned pack16(_Float16 a, _Float16 b) {
  union { _Float16 h[2]; unsigned u; } cv;
  cv.h[0] = a; cv.h[1] = b;
  return cv.u;
}

// ---------------- fence-free barrier (R5-proven) ---------------------------
__device__ __forceinline__ void bar_arrive(int* b) {
  __syncthreads();
  if (threadIdx.x == 0) atomicAdd(b, 1);
}
__device__ __forceinline__ void bar_wait(int* b, int target) {
  if (threadIdx.x == 0) {
    int guard = 0;
    while (__hip_atomic_load(b, __ATOMIC_RELAXED,
                             __HIP_MEMORY_SCOPE_AGENT) < target) {
      __builtin_amdgcn_s_sleep(16);
      if (++guard > (1 << 22)) break;  // hang guard
    }
  }
  __syncthreads();
}

// ---------------- merged prep (R5-identical) -------------------------------
struct WArgs {
  const float* s[7];
  _Float16* h[7];
  _Float16* l[7];
};
__global__ __launch_bounds__(256) void prep_split(
    WArgs a, const float* __restrict__ flow, const float* __restrict__ bk,
    const float* __restrict__ bv, const float* __restrict__ bsh,
    _Float16* __restrict__ fh, _Float16* __restrict__ fl,
    float* __restrict__ kvb, int* __restrict__ cnt) {
  __shared__ float tile[64][65];
  const int bid = blockIdx.x, t = threadIdx.x;
  if (bid == 2915) {  // zero election counters (1024) + barriers (64)
#pragma unroll
    for (int i = 0; i < 5; i++) {
      int idx = i * 256 + t;
      if (idx < 1088) cnt[idx] = 0;
    }
    return;
  }
  if (bid < 275) {
    if (bid < 256) {
      const int base = (bid * 256 + t) * 4;
      float4 v = *(const float4*)&flow[base];
      float x[4] = {v.x, v.y, v.z, v.w};
#pragma unroll
      for (int j = 0; j < 4; j++) {
        _Float16 h, l;
        split16(x[j], h, l);
        fh[base + j] = h;
        fl[base + j] = l;
      }
    } else {
      const int idx = (bid - 256) * 256 + t;
      if (idx < KVN + HD) {
        float bb = (idx < 2048) ? bk[idx]
                 : (idx < 4096) ? bv[idx - 2048]
                                : bsh[idx - 4096];
        kvb[idx] = bb;
      }
    }
    return;
  }
  const int WS_OFF[8] = {0, 64, 320, 576, 1088, 2112, 2624, 2640};
  const int WS_K[7] = {512, 512, 512, 512, 1024, 1024, 512};
  const int WS_N[7] = {512, 64, 64, 1024, 1024, 512, 128};
  int wb = bid - 275;
  int mi = 0;
  while (wb >= WS_OFF[mi + 1]) mi++;
  int tt = wb - WS_OFF[mi];
  const int K = WS_K[mi], N = WS_N[mi];
  const int ktiles = K >> 6;
  const int per = ktiles * (N >> 6);
  const int z = tt / per;
  const int rem = tt - z * per;
  const int k0 = (rem % ktiles) * 64, n0 = (rem / ktiles) * 64;
  const size_t moff = (size_t)z * K * N;
  const float* src = a.s[mi] + moff;
  _Float16* dh = a.h[mi] + moff;
  _Float16* dl = a.l[mi] + moff;
#pragma unroll
  for (int i = 0; i < 16; i++) {
    int idx = i * 256 + t, r = idx >> 6, c = idx & 63;
    tile[r][c] = src[(size_t)(k0 + r) * N + n0 + c];
  }
  __syncthreads();
#pragma unroll
  for (int i = 0; i < 16; i++) {
    int idx = i * 256 + t, n = idx >> 6, k = idx & 63;
    float v = tile[k][n];
    _Float16 h, l;
    split16(v, h, l);
    dh[(size_t)(n0 + n) * K + k0 + k] = h;
    dl[(size_t)(n0 + n) * K + k0 + k] = l;
  }
}

// ---------------- 64x64 MFMA GEMM core macro-body (verified) ---------------
// NORMAL cached staging everywhere: all A/B operands are write-once buffers.
#define GEMM64_BODY(Ah, Al, Bh, Bl, K, m0, n0, kbase, kchunk, hh, mid, lds)  \
  {                                                                          \
    const int t = threadIdx.x, lane = t & 63, wave = t >> 6;                 \
    const int KT = (kchunk) >> 5;                                            \
    const int l15w = lane & 15, quadw = lane >> 4;                           \
    const _Float16* srcs[4] = {                                              \
        (Ah) + (size_t)(m0) * (K), (Al) + (size_t)(m0) * (K),                \
        (Bh) + (size_t)(n0) * (K), (Bl) + (size_t)(n0) * (K)};               \
    const _Float16* gsrc =                                                   \
        srcs[wave] + (size_t)l15w * (K) + quadw * 8 + (kbase);               \
    auto stage = [&](int buf, int kt) {                                      \
      _Float16* base = &lds[buf * 8192 + wave * 2048];                       \
      const int koff = kt * 32;                                              \
      _Pragma("unroll") for (int f = 0; f < 4; f++)                          \
          __builtin_amdgcn_global_load_lds(                                  \
              gsrc + (size_t)(f * 16) * (K) + koff, base + f * 512, 16, 0,   \
              0);                                                            \
    };                                                                       \
    const int wm = wave >> 1, wn = wave & 1;                                 \
    stage(0, 0);                                                             \
    __syncthreads();                                                         \
    for (int kt = 0; kt < KT; kt++) {                                        \
      if (kt + 1 < KT) stage((kt + 1) & 1, kt + 1);                          \
      const int bofs = (kt & 1) * 8192;                                      \
      half8 a_h[2], a_l[2], b_h[2], b_l[2];                                  \
      _Pragma("unroll") for (int i = 0; i < 2; i++) {                        \
        const int af = (wm * 2 + i) * 512 + lane * 8;                        \
        const int bf = (wn * 2 + i) * 512 + lane * 8;                        \
        a_h[i] = *(const half8*)&lds[bofs + af];                             \
        a_l[i] = *(const half8*)&lds[bofs + 2048 + af];                      \
        b_h[i] = *(const half8*)&lds[bofs + 4096 + bf];                      \
        b_l[i] = *(const half8*)&lds[bofs + 6144 + bf];                      \
      }                                                                      \
      _Pragma("unroll") for (int i = 0; i < 2; i++)                          \
          _Pragma("unroll") for (int j = 0; j < 2; j++) {                    \
        hh[i][j] = __builtin_amdgcn_mfma_f32_16x16x32_f16(a_h[i], b_h[j],    \
                                                          hh[i][j], 0, 0, 0);\
        mid[i][j] = __builtin_amdgcn_mfma_f32_16x16x32_f16(                  \
            a_h[i], b_l[j], mid[i][j], 0, 0, 0);                             \
        mid[i][j] = __builtin_amdgcn_mfma_f32_16x16x32_f16(                  \
            a_l[i], b_h[j], mid[i][j], 0, 0, 0);                             \
      }                                                                      \
      __syncthreads();                                                       \
    }                                                                        \
  }

#define GEMM_ACC_INIT(hh, mid)                                               \
  floatx4 hh[2][2], mid[2][2];                                               \
  _Pragma("unroll") for (int i = 0; i < 2; i++)                              \
      _Pragma("unroll") for (int j = 0; j < 2; j++) {                        \
    hh[i][j] = (floatx4){0.f, 0.f, 0.f, 0.f};                                \
    mid[i][j] = (floatx4){0.f, 0.f, 0.f, 0.f};                               \
  }

#define PARTIAL_EPI(Pz, Ndim, m0, n0, hh, mid)                               \
  {                                                                          \
    const int t = threadIdx.x, lane = t & 63, wave = t >> 6;                 \
    const int wm = wave >> 1, wn = wave & 1, quad = lane >> 4,               \
              l15 = lane & 15;                                               \
    _Pragma("unroll") for (int i = 0; i < 2; i++)                            \
        _Pragma("unroll") for (int j = 0; j < 2; j++)                        \
            _Pragma("unroll") for (int r = 0; r < 4; r++) {                  \
      float v = hh[i][j][r] + mid[i][j][r] * (1.0f / 2048.0f);               \
      const int m = (m0) + (wm * 2 + i) * 16 + quad * 4 + r;                 \
      const int n = (n0) + (wn * 2 + j) * 16 + l15;                          \
      (Pz)[(size_t)m * (Ndim) + n] = v;                                      \
    }                                                                        \
  }

#define PARTIAL_EPI_COH(Pz, Ndim, m0, n0, hh, mid)                           \
  {                                                                          \
    const int t = threadIdx.x, lane = t & 63, wave = t >> 6;                 \
    const int wm = wave >> 1, wn = wave & 1, quad = lane >> 4,               \
              l15 = lane & 15;                                               \
    _Pragma("unroll") for (int i = 0; i < 2; i++)                            \
        _Pragma("unroll") for (int j = 0; j < 2; j++)                        \
            _Pragma("unroll") for (int r = 0; r < 4; r++) {                  \
      float v = hh[i][j][r] + mid[i][j][r] * (1.0f / 2048.0f);               \
      const int m = (m0) + (wm * 2 + i) * 16 + quad * 4 + r;                 \
      const int n = (n0) + (wn * 2 + j) * 16 + l15;                          \
      coh_st(&(Pz)[(size_t)m * (Ndim) + n], v);                              \
    }                                                                        \
  }

// ================= fallback standalone kernels (R0-verified path) ==========
__global__ __launch_bounds__(256) void gemm_kv(
    const _Float16* __restrict__ Ah, const _Float16* __restrict__ Al,
    const _Float16* __restrict__ Bh, const _Float16* __restrict__ Bl,
    const float* __restrict__ kvb, float* __restrict__ kv,
    float* __restrict__ att) {
  __shared__ __align__(16) _Float16 lds[2 * 8192];
  const int n0 = blockIdx.x * 64, m0 = blockIdx.y * 64;
  GEMM_ACC_INIT(hh, mid)
  GEMM64_BODY(Ah, Al, Bh, Bl, 512, m0, n0, 0, 512, hh, mid, lds)
  const int t = threadIdx.x, lane = t & 63, wave = t >> 6;
  const int wm = wave >> 1, wn = wave & 1, quad = lane >> 4, l15 = lane & 15;
#pragma unroll
  for (int i = 0; i < 2; i++)
#pragma unroll
    for (int j = 0; j < 2; j++)
#pragma unroll
      for (int r = 0; r < 4; r++) {
        float v = hh[i][j][r] + mid[i][j][r] * (1.0f / 2048.0f);
        const int m = m0 + (wm * 2 + i) * 16 + quad * 4 + r;
        const int n = n0 + (wn * 2 + j) * 16 + l15;
        v += kvb[n];
        if (n < KVN) kv[(size_t)m * KVN + n] = v;
        else att[(size_t)m * HD + (n - KVN)] = v;
      }
}

__global__ __launch_bounds__(256) void gemm_sp(
    const _Float16* __restrict__ Ah, const _Float16* __restrict__ Al,
    const _Float16* __restrict__ Bh, const _Float16* __restrict__ Bl,
    float* __restrict__ P, int K, int kchunk, int Ndim) {
  __shared__ __align__(16) _Float16 lds[2 * 8192];
  const int n0 = blockIdx.x * 64, m0 = blockIdx.y * 64;
  const int kbase = blockIdx.z * kchunk;
  GEMM_ACC_INIT(hh, mid)
  GEMM64_BODY(Ah, Al, Bh, Bl, K, m0, n0, kbase, kchunk, hh, mid, lds)
  float* Pz = P + (size_t)blockIdx.z * ROWS * Ndim;
  PARTIAL_EPI(Pz, Ndim, m0, n0, hh, mid)
}

__global__ __launch_bounds__(256) void epi_h(
    const float* __restrict__ P, const float* __restrict__ bias,
    _Float16* __restrict__ Oh, _Float16* __restrict__ Ol, int Ndim, int kz,
    int relu) {
  const int n = blockIdx.x * 256 + threadIdx.x;
  const int m = blockIdx.y;
  const size_t MN = (size_t)ROWS * Ndim;
  const size_t id = (size_t)m * Ndim + n;
  float v = 0.0f;
  for (int z = 0; z < kz; z++) v += P[z * MN + id];
  v += bias[n];
  if (relu) v = fmaxf(v, 0.0f);
  _Float16 h, l;
  split16(v, h, l);
  Oh[id] = h;
  Ol[id] = l;
}

__global__ __launch_bounds__(256) void gemm_dist(
    const _Float16* __restrict__ Ah, const _Float16* __restrict__ Al,
    const _Float16* __restrict__ Bh, const _Float16* __restrict__ Bl,
    const float* __restrict__ bd, float* __restrict__ logits) {
  __shared__ __align__(16) _Float16 lds[2 * 8192];
  const int n0 = blockIdx.x * 64, m0 = blockIdx.y * 64;
  GEMM_ACC_INIT(hh, mid)
  GEMM64_BODY(Ah, Al, Bh, Bl, 512, m0, n0, 0, 512, hh, mid, lds)
  const int t = threadIdx.x, lane = t & 63, wave = t >> 6;
  const int wm = wave >> 1, wn = wave & 1, quad = lane >> 4, l15 = lane & 15;
#pragma unroll
  for (int i = 0; i < 2; i++)
#pragma unroll
    for (int j = 0; j < 2; j++)
#pragma unroll
      for (int r = 0; r < 4; r++) {
        float v = hh[i][j][r] + mid[i][j][r] * (1.0f / 2048.0f);
        const int m = m0 + (wm * 2 + i) * 16 + quad * 4 + r;
        const int n = n0 + (wn * 2 + j) * 16 + l15;
        logits[(size_t)m * R + n] = v + bd[n];
      }
}

__device__ __forceinline__ void attn_core(
    float* __restrict__ att, _Float16* __restrict__ att_h,
    _Float16* __restrict__ att_l, const float* __restrict__ kv,
    const float* __restrict__ g, const float* __restrict__ bb, int l, int row,
    float q0, float q1) {
  __shared__ float q[HD];
  __shared__ float sp[HD];
  __shared__ double rb[8];
  const int t = threadIdx.x;
  const int b_ = row >> 6;
  q[t] = q0;
  q[t + 256] = q1;
  __syncthreads();
#pragma unroll
  for (int rep = 0; rep < 2; rep++) {
    int idx = t + rep * 256;
    int h = idx >> 6, w = idx & 63;
    const float* kp = kv + (size_t)(b_ * 64 + w) * KVN + (l * 8 + h) * 64;
    const float* qp = q + h * D;
    double s = 0.0;
#pragma unroll 8
    for (int d = 0; d < 64; d++) s += (double)qp[d] * (double)kp[d];
    sp[idx] = (float)s * 0.125f;
  }
  __syncthreads();
  {
    int h = t >> 5, w0 = t & 31;
    float s0 = sp[h * 64 + w0], s1 = sp[h * 64 + w0 + 32];
    float mx = fmaxf(s0, s1);
#pragma unroll
    for (int m = 16; m; m >>= 1) mx = fmaxf(mx, __shfl_xor(mx, m, 32));
    float e0 = expf(s0 - mx), e1 = expf(s1 - mx);
    double sm = (double)e0 + (double)e1;
#pragma unroll
    for (int m = 16; m; m >>= 1) sm += __shfl_xor(sm, m, 32);
    sp[h * 64 + w0]      = (float)((double)e0 / sm);
    sp[h * 64 + w0 + 32] = (float)((double)e1 / sm);
  }
  __syncthreads();
  float x[2];
#pragma unroll
  for (int rep = 0; rep < 2; rep++) {
    int idx = t + rep * 256;
    int h = idx >> 6, d = idx & 63;
    const float* vp =
        kv + (size_t)(b_ * 64) * KVN + 2048 + (l * 8 + h) * 64 + d;
    const float* pp = sp + h * 64;
    double acc = 0.0;
#pragma unroll 8
    for (int w = 0; w < 64; w++)
      acc += (double)pp[w] * (double)vp[(size_t)w * KVN];
    x[rep] = q[idx] + (float)acc;
  }
  double s1 = (double)x[0] + (double)x[1];
  double s2 = (double)x[0] * (double)x[0] + (double)x[1] * (double)x[1];
  s1 = waveReduceAdd64(s1);
  s2 = waveReduceAdd64(s2);
  const int wid = t >> 6, lane = t & 63;
  if (lane == 0) { rb[wid] = s1; rb[4 + wid] = s2; }
  __syncthreads();
  double S1 = rb[0] + rb[1] + rb[2] + rb[3];
  double S2 = rb[4] + rb[5] + rb[6] + rb[7];
  double mean = S1 / (double)HD;
  double var  = S2 / (double)HD - mean * mean;
  double inv  = 1.0 / sqrt(var + (double)1e-5f);
  float y0 =
      (float)(((double)x[0] - mean) * inv * (double)g[t] + (double)bb[t]);
  float y1 = (float)(((double)x[1] - mean) * inv * (double)g[t + 256] +
                     (double)bb[t + 256]);
  att[row * HD + t] = y0;
  att[row * HD + 256 + t] = y1;
  _Float16 h0, l0, h1v, l1v;
  split16(y0, h0, l0);
  split16(y1, h1v, l1v);
  att_h[row * HD + t] = h0;
  att_l[row * HD + t] = l0;
  att_h[row * HD + 256 + t] = h1v;
  att_l[row * HD + 256 + t] = l1v;
}

__global__ __launch_bounds__(256) void attn_kernel(
    float* __restrict__ att, _Float16* __restrict__ att_h,
    _Float16* __restrict__ att_l, const float* __restrict__ kv,
    const float* __restrict__ g, const float* __restrict__ bb, int l) {
  const int t = threadIdx.x, row = blockIdx.x;
  float q0 = att[row * HD + t];
  float q1 = att[row * HD + 256 + t];
  attn_core(att, att_h, att_l, kv, g, bb, l, row, q0, q1);
}

__global__ __launch_bounds__(256) void epi_ln_attn(
    float* __restrict__ att, _Float16* __restrict__ att_h,
    _Float16* __restrict__ att_l, const float* __restrict__ P,
    const float* __restrict__ b3, const float* __restrict__ g2,
    const float* __restrict__ bb2, const float* __restrict__ kv,
    const float* __restrict__ g1, const float* __restrict__ bb1, int next_l,
    int kz) {
  __shared__ double rb[8];
  const int t = threadIdx.x, row = blockIdx.x;
  const size_t MN = (size_t)ROWS * HD;
  const size_t id0 = (size_t)row * HD + t;
  float h0 = 0.0f, h1s = 0.0f;
  for (int z = 0; z < kz; z++) {
    h0 += P[z * MN + id0];
    h1s += P[z * MN + id0 + 256];
  }
  h0 += b3[t];
  h1s += b3[t + 256];
  float x0 = att[id0] + h0;
  float x1 = att[id0 + 256] + h1s;
  double s1 = (double)x0 + (double)x1;
  double s2 = (double)x0 * (double)x0 + (double)x1 * (double)x1;
  s1 = waveReduceAdd64(s1);
  s2 = waveReduceAdd64(s2);
  const int wid = t >> 6, lane = t & 63;
  if (lane == 0) { rb[wid] = s1; rb[4 + wid] = s2; }
  __syncthreads();
  double S1 = rb[0] + rb[1] + rb[2] + rb[3];
  double S2 = rb[4] + rb[5] + rb[6] + rb[7];
  double mean = S1 / (double)HD;
  double var  = S2 / (double)HD - mean * mean;
  double inv  = 1.0 / sqrt(var + (double)1e-5f);
  float y0 =
      (float)(((double)x0 - mean) * inv * (double)g2[t] + (double)bb2[t]);
  float y1 = (float)(((double)x1 - mean) * inv * (double)g2[t + 256] +
                     (double)bb2[t + 256]);
  if (next_l < 0) {
    att[id0] = y0;
    att[id0 + 256] = y1;
    _Float16 hh0, ll0, hh1, ll1;
    split16(y0, hh0, ll0);
    split16(y1, hh1, ll1);
    att_h[id0] = hh0;
    att_l[id0] = ll0;
    att_h[id0 + 256] = hh1;
    att_l[id0 + 256] = ll1;
  } else {
    __syncthreads();
    attn_core(att, att_h, att_l, kv, g1, bb1, next_l, row, y0, y1);
  }
}

__global__ __launch_bounds__(256) void sample_kernel(
    const float* __restrict__ logits, float* __restrict__ out) {
  constexpr TF2 KC = threefry(0u, 1u, 0u, 0u);
  constexpr TF2 KU = threefry(0u, 1u, 0u, 1u);
  const int lane = threadIdx.x & 63;
  const int wid = threadIdx.x >> 6;
  const int row = blockIdx.x * 4 + wid;
  const float* lrow = logits + (row >> 5) * R;
  float bvv = -1e30f;
  int bi = 0;
#pragma unroll
  for (int rep = 0; rep < 2; rep++) {
    int r = lane + rep * 64;
    unsigned j = (unsigned)row * (unsigned)R + (unsigned)r;
    unsigned bits = tf_bits32(KC.a, KC.b, j);
    float f = __uint_as_float((bits >> 9) | 0x3f800000u) - 1.0f;
    float u = fmaxf(f, 1.17549435e-38f);
    float gv = -logf(-logf(u));
    float v = lrow[r] + gv;
    if (v > bvv) { bvv = v; bi = r; }
  }
#pragma unroll
  for (int m = 32; m; m >>= 1) {
    float ov = __shfl_xor(bvv, m, 64);
    int oi = __shfl_xor(bi, m, 64);
    if (ov > bvv || (ov == bvv && oi < bi)) { bvv = ov; bi = oi; }
  }
  if (lane == 0) {
    unsigned ub = tf_bits32(KU.a, KU.b, (unsigned)row);
    float u = __uint_as_float((ub >> 9) | 0x3f800000u) - 1.0f;
    out[row] = ((float)bi + u) * (1.0f / 128.0f);
  }
}

// ================= mega3: one persistent kernel, write-once versioning =====
// Memory model: cross-stage producers store sc0sc1 (LLC-visible, no wbl2);
// barriers = vmcnt-drain + device atomicAdd + relaxed spin (R5-proven).
// Consumers use NORMAL cached loads: every consumed buffer is WRITE-ONCE
// within this kernel (versioned), so no L2 can hold a stale copy.
// P and logits are single-version: P read via agent loads; logits read
// normally (written once, never cached by readers before the write).
struct M3 {
  float *attB, *kv, *P, *logits, *out;
  const float *kvb, *b1, *b2, *b3, *ln1g, *ln1b, *ln2g, *ln2b, *bd;
  const _Float16 *flow_h, *flow_l, *BKV_h, *BKV_l;
  const _Float16 *W1_h, *W1_l, *W2_h, *W2_l, *W3_h, *W3_l, *Wd_h, *Wd_l;
  _Float16 *ahB, *alB, *h1hB, *h1lB, *h2hB, *h2lB;
  int *cnt, *bar;
};

// attention core: NORMAL kv loads (write-once), sc1 outputs.
// thread t <-> cols (2t, 2t+1)  [R5-verified math, absmax 0]
__device__ void attn_core3(float* attOut, _Float16* ahOut, _Float16* alOut,
                           const float* kv, const float* g, const float* bb,
                           int l, int row, float q0, float q1) {
  __shared__ float q[HD];
  __shared__ float sp[HD];
  __shared__ double rb[8];
  const int t = threadIdx.x;
  const int b_ = row >> 6;
  q[2 * t] = q0;
  q[2 * t + 1] = q1;
  __syncthreads();
#pragma unroll
  for (int rep = 0; rep < 2; rep++) {
    int idx = t + rep * 256;
    int h = idx >> 6, w = idx & 63;
    const float* kp = kv + (size_t)(b_ * 64 + w) * KVN + (l * 8 + h) * 64;
    const float* qp = q + h * D;
    double s = 0.0;
#pragma unroll 8
    for (int dd = 0; dd < 32; dd++) {
      float2 kk = ((const float2*)kp)[dd];
      s += (double)qp[2 * dd] * (double)kk.x;
      s += (double)qp[2 * dd + 1] * (double)kk.y;
    }
    sp[idx] = (float)s * 0.125f;
  }
  __syncthreads();
  {
    int h = t >> 5, w0 = t & 31;
    float s0 = sp[h * 64 + w0], s1 = sp[h * 64 + w0 + 32];
    float mx = fmaxf(s0, s1);
#pragma unroll
    for (int m = 16; m; m >>= 1) mx = fmaxf(mx, __shfl_xor(mx, m, 32));
    float e0 = expf(s0 - mx), e1 = expf(s1 - mx);
    double sm = (double)e0 + (double)e1;
#pragma unroll
    for (int m = 16; m; m >>= 1) sm += __shfl_xor(sm, m, 32);
    sp[h * 64 + w0]      = (float)((double)e0 / sm);
    sp[h * 64 + w0 + 32] = (float)((double)e1 / sm);
  }
  __syncthreads();
  float x[2];
#pragma unroll
  for (int rep = 0; rep < 2; rep++) {
    int col = 2 * t + rep;
    int h = col >> 6, d = col & 63;
    const float* vp =
        kv + (size_t)(b_ * 64) * KVN + 2048 + (l * 8 + h) * 64 + d;
    const float* pp = sp + h * 64;
    double acc = 0.0;
#pragma unroll 8
    for (int w = 0; w < 64; w++)
      acc += (double)pp[w] * (double)vp[(size_t)w * KVN];
    x[rep] = q[col] + (float)acc;
  }
  double s1 = (double)x[0] + (double)x[1];
  double s2 = (double)x[0] * (double)x[0] + (double)x[1] * (double)x[1];
  s1 = waveReduceAdd64(s1);
  s2 = waveReduceAdd64(s2);
  const int wid = t >> 6, lane = t & 63;
  if (lane == 0) { rb[wid] = s1; rb[4 + wid] = s2; }
  __syncthreads();
  double S1 = rb[0] + rb[1] + rb[2] + rb[3];
  double S2 = rb[4] + rb[5] + rb[6] + rb[7];
  double mean = S1 / (double)HD;
  double var  = S2 / (double)HD - mean * mean;
  double inv  = 1.0 / sqrt(var + (double)1e-5f);
  float y0 = (float)(((double)x[0] - mean) * inv * (double)g[2 * t] +
                     (double)bb[2 * t]);
  float y1 = (float)(((double)x[1] - mean) * inv * (double)g[2 * t + 1] +
                     (double)bb[2 * t + 1]);
  union { unsigned long long u; float f[2]; } pr;
  pr.f[0] = y0; pr.f[1] = y1;
  coh_st64((unsigned long long*)(attOut + (size_t)row * HD + 2 * t), pr.u);
  _Float16 h0, l0, h1v, l1v;
  split16(y0, h0, l0);
  split16(y1, h1v, l1v);
  coh_st32((unsigned*)ahOut + (size_t)row * 256 + t, pack16(h0, h1v));
  coh_st32((unsigned*)alOut + (size_t)row * 256 + t, pack16(l0, l1v));
}

__device__ void kv_job3(const M3& A, int job, _Float16* lds) {
  const int n0 = (job % 72) * 64, m0 = (job / 72) * 64;
  GEMM_ACC_INIT(hh, mid)
  GEMM64_BODY(A.flow_h, A.flow_l, A.BKV_h, A.BKV_l, 512, m0, n0, 0, 512,
              hh, mid, lds)
  const int t0 = threadIdx.x, lane = t0 & 63, wave = t0 >> 6;
  const int wm = wave >> 1, wn = wave & 1, quad = lane >> 4, l15 = lane & 15;
#pragma unroll
  for (int i = 0; i < 2; i++)
#pragma unroll
    for (int j = 0; j < 2; j++)
#pragma unroll
      for (int r = 0; r < 4; r++) {
        float v = hh[i][j][r] + mid[i][j][r] * (1.0f / 2048.0f);
        const int m = m0 + (wm * 2 + i) * 16 + quad * 4 + r;
        const int n = n0 + (wn * 2 + j) * 16 + l15;
        v += A.kvb[n];
        if (n < KVN) coh_st(&A.kv[(size_t)m * KVN + n], v);
        else coh_st(&A.attB[(size_t)m * HD + (n - KVN)], v);  // att v0
      }
}

// split-K GEMM + fence-free last-block fixup (W1/W2)
template <int KZ>
__device__ void w_job3(const _Float16* Ah, const _Float16* Al,
                       const _Float16* Bh, const _Float16* Bl, float* P,
                       const float* bias, _Float16* Oh, _Float16* Ol,
                       int* cnt, int* bar, int K, int kchunk, int Ndim,
                       int n0, int m0, int z, _Float16* lds) {
  __shared__ int isL;
  GEMM_ACC_INIT(hh, mid)
  GEMM64_BODY(Ah, Al, Bh, Bl, K, m0, n0, z * kchunk, kchunk, hh, mid, lds)
  float* Pz = P + (size_t)z * ROWS * Ndim;
  PARTIAL_EPI_COH(Pz, Ndim, m0, n0, hh, mid)
  __syncthreads();  // vmcnt(0) drain: partials at coherence point
  const int tile = (m0 >> 6) * (Ndim >> 6) + (n0 >> 6);
  if (threadIdx.x == 0) isL = (atomicAdd(&cnt[tile], 1) == KZ - 1) ? 1 : 0;
  __syncthreads();
  if (isL) {
    const size_t MN = (size_t)ROWS * Ndim;
    unsigned* Oh2 = (unsigned*)Oh;
    unsigned* Ol2 = (unsigned*)Ol;
#pragma unroll
    for (int it = 0; it < 8; it++) {
      const int p = it * 256 + threadIdx.x;
      const int m = m0 + (p >> 5), n = n0 + ((p & 31) << 1);
      const size_t id = (size_t)m * Ndim + n;
      float v0 = 0.f, v1 = 0.f;
#pragma unroll
      for (int zz = 0; zz < KZ; zz++) {
        v0 += coh_ld(&P[zz * MN + id]);
        v1 += coh_ld(&P[zz * MN + id + 1]);
      }
      v0 = fmaxf(v0 + bias[n], 0.f);
      v1 = fmaxf(v1 + bias[n + 1], 0.f);
      _Float16 h0, l0, h1, l1;
      split16(v0, h0, l0);
      split16(v1, h1, l1);
      coh_st32(&Oh2[id >> 1], pack16(h0, h1));
      coh_st32(&Ol2[id >> 1], pack16(l0, l1));
    }
    __syncthreads();  // drain fixup stores before barrier bump
    if (threadIdx.x == 0) atomicAdd(bar, 1);
  }
}

__device__ void epi3(const M3& A, int l, int next_l, int row) {
  __shared__ double rbE[8];
  const int t = threadIdx.x;
  const size_t MN = (size_t)ROWS * HD;
  const size_t id0 = (size_t)row * HD + 2 * t;
  float h0 = 0.0f, h1s = 0.0f;
#pragma unroll
  for (int z = 0; z < 8; z++) {
    h0 += coh_ld(&A.P[z * MN + id0]);
    h1s += coh_ld(&A.P[z * MN + id0 + 1]);
  }
  h0 += A.b3[l * HD + 2 * t];
  h1s += A.b3[l * HD + 2 * t + 1];
  const float* attRes = A.attB + (size_t)(1 + l) * ATT_STR;  // att v(1+l)
  float2 rr = *(const float2*)&attRes[id0];
  float x0 = rr.x + h0;
  float x1 = rr.y + h1s;
  double s1 = (double)x0 + (double)x1;
  double s2 = (double)x0 * (double)x0 + (double)x1 * (double)x1;
  s1 = waveReduceAdd64(s1);
  s2 = waveReduceAdd64(s2);
  const int wid = t >> 6, lane = t & 63;
  if (lane == 0) { rbE[wid] = s1; rbE[4 + wid] = s2; }
  __syncthreads();
  double S1 = rbE[0] + rbE[1] + rbE[2] + rbE[3];
  double S2 = rbE[4] + rbE[5] + rbE[6] + rbE[7];
  double mean = S1 / (double)HD;
  double var  = S2 / (double)HD - mean * mean;
  double inv  = 1.0 / sqrt(var + (double)1e-5f);
  const float* g2 = A.ln2g + l * HD;
  const float* bb2 = A.ln2b + l * HD;
  float y0 = (float)(((double)x0 - mean) * inv * (double)g2[2 * t] +
                     (double)bb2[2 * t]);
  float y1 = (float)(((double)x1 - mean) * inv * (double)g2[2 * t + 1] +
                     (double)bb2[2 * t + 1]);
  if (next_l < 0) {
    float* attOut = A.attB + 5 * ATT_STR;
    _Float16* ahOut = A.ahB + 5 * AH_STR;
    _Float16* alOut = A.alB + 5 * AH_STR;
    union { unsigned long long u; float f[2]; } pr;
    pr.f[0] = y0; pr.f[1] = y1;
    coh_st64((unsigned long long*)(attOut + id0), pr.u);
    _Float16 hh0, ll0, hh1, ll1;
    split16(y0, hh0, ll0);
    split16(y1, hh1, ll1);
    coh_st32((unsigned*)ahOut + (size_t)row * 256 + t, pack16(hh0, hh1));
    coh_st32((unsigned*)alOut + (size_t)row * 256 + t, pack16(ll0, ll1));
  } else {
    __syncthreads();
    attn_core3(A.attB + (size_t)(2 + l) * ATT_STR,
               A.ahB + (size_t)(2 + l) * AH_STR,
               A.alB + (size_t)(2 + l) * AH_STR, A.kv,
               A.ln1g + next_l * HD, A.ln1b + next_l * HD, next_l, row, y0,
               y1);
  }
}

__global__ __launch_bounds__(256, 2) void mega3(M3 A) {
  __shared__ __align__(16) _Float16 lds[2 * 8192];
  const int bid = blockIdx.x, t = threadIdx.x;
  int* bar = A.bar;

  // ---- P0: kv|shift GEMM, 576 jobs -> kv + att v0 ----
  kv_job3(A, bid, lds);
  if (bid < 64) kv_job3(A, bid + 512, lds);
  bar_arrive(&bar[0]);
  bar_wait(&bar[0], 512);

  // ---- P1: attention layer 0 (row = bid): att v0 -> v1 ----
  {
    float2 qq = *(const float2*)&A.attB[(size_t)bid * HD + 2 * t];
    attn_core3(A.attB + ATT_STR, A.ahB + AH_STR, A.alB + AH_STR, A.kv,
               A.ln1g, A.ln1b, 0, bid, qq.x, qq.y);
  }
  bar_arrive(&bar[1]);
  bar_wait(&bar[1], 512);

  // ---- transformer layers ----
  for (int l = 0; l < L; l++) {
    const _Float16* ahIn = A.ahB + (size_t)(1 + l) * AH_STR;
    const _Float16* alIn = A.alB + (size_t)(1 + l) * AH_STR;
    _Float16* h1h = A.h1hB + (size_t)l * H1_STR;
    _Float16* h1l = A.h1lB + (size_t)l * H1_STR;
    _Float16* h2h = A.h2hB + (size_t)l * H1_STR;
    _Float16* h2l = A.h2lB + (size_t)l * H1_STR;
    {  // W1: 128 tiles x kz4, kchunk 128 -> h1[l]
      const int tile = bid & 127, z = bid >> 7;
      w_job3<4>(ahIn, alIn, A.W1_h + (size_t)l * 524288,
                A.W1_l + (size_t)l * 524288, A.P, A.b1 + l * M, h1h, h1l,
                A.cnt + (l * 2) * 128, &bar[2 + l * 4], 512, 128, M,
                (tile & 15) * 64, (tile >> 4) * 64, z, lds);
    }
    bar_wait(&bar[2 + l * 4], 128);
#pragma unroll
    for (int jj = 0; jj < 2; jj++) {  // W2: 128 tiles x kz8 -> h2[l]
      const int job = bid + jj * 512;
      const int tile = job & 127, z = job >> 7;
      w_job3<8>(h1h, h1l, A.W2_h + (size_t)l * 1048576,
                A.W2_l + (size_t)l * 1048576, A.P, A.b2 + l * M, h2h, h2l,
                A.cnt + (l * 2 + 1) * 128, &bar[3 + l * 4], 1024, 128, M,
                (tile & 15) * 64, (tile >> 4) * 64, z, lds);
    }
    bar_wait(&bar[3 + l * 4], 128);
    {  // W3: 64 tiles x kz8 -> P partials only
      const int tile = bid & 63, z = bid >> 6;
      const int n0 = (tile & 7) * 64, m0 = (tile >> 3) * 64;
      GEMM_ACC_INIT(hh, mid)
      GEMM64_BODY(h2h, h2l, A.W3_h + (size_t)l * 524288,
                  A.W3_l + (size_t)l * 524288, 1024, m0, n0, z * 128, 128,
                  hh, mid, lds)
      float* Pz = A.P + (size_t)z * ROWS * HD;
      PARTIAL_EPI_COH(Pz, HD, m0, n0, hh, mid)
    }
    bar_arrive(&bar[4 + l * 4]);
    bar_wait(&bar[4 + l * 4], 512);
    epi3(A, l, (l + 1 < L) ? (l + 1) : -1, bid);
    bar_arrive(&bar[5 + l * 4]);
    bar_wait(&bar[5 + l * 4], 512);
  }

  // ---- dist head: 16 direct tiles, A = att_h v5 ----
  if (bid < 16) {
    const int n0 = (bid & 1) * 64, m0 = (bid >> 1) * 64;
    GEMM_ACC_INIT(hh, mid)
    GEMM64_BODY(A.ahB + 5 * AH_STR, A.alB + 5 * AH_STR, A.Wd_h, A.Wd_l, 512,
                m0, n0, 0, 512, hh, mid, lds)
    const int lane = t & 63, wave = t >> 6;
    const int wm = wave >> 1, wn = wave & 1, quad = lane >> 4,
              l15 = lane & 15;
#pragma unroll
    for (int i = 0; i < 2; i++)
#pragma unroll
      for (int j = 0; j < 2; j++)
#pragma unroll
        for (int r = 0; r < 4; r++) {
          float v = hh[i][j][r] + mid[i][j][r] * (1.0f / 2048.0f);
          const int m = m0 + (wm * 2 + i) * 16 + quad * 4 + r;
          const int n = n0 + (wn * 2 + j) * 16 + l15;
          coh_st(&A.logits[(size_t)m * R + n], v + A.bd[n]);
        }
  }
  bar_arrive(&bar[18]);
  bar_wait(&bar[18], 512);

  // ---- gumbel-argmax sampling (logits write-once -> normal loads) ----
  {
    constexpr TF2 KC = threefry(0u, 1u, 0u, 0u);
    constexpr TF2 KU = threefry(0u, 1u, 0u, 1u);
    const int lane = t & 63, wid = t >> 6;
    for (int row = bid * 4 + wid; row < SROWS; row += 2048) {
      const float* lrow = A.logits + (row >> 5) * R;
      float bvv = -1e30f;
      int bi = 0;
#pragma unroll
      for (int rep = 0; rep < 2; rep++) {
        int r = lane + rep * 64;
        unsigned j = (unsigned)row * (unsigned)R + (unsigned)r;
        unsigned bits = tf_bits32(KC.a, KC.b, j);
        float f = __uint_as_float((bits >> 9) | 0x3f800000u) - 1.0f;
        float u = fmaxf(f, 1.17549435e-38f);
        float gv = -logf(-logf(u));
        float v = lrow[r] + gv;
        if (v > bvv) { bvv = v; bi = r; }
      }
#pragma unroll
      for (int m = 32; m; m >>= 1) {
        float ov = __shfl_xor(bvv, m, 64);
        int oi = __shfl_xor(bi, m, 64);
        if (ov > bvv || (ov == bvv && oi < bi)) { bvv = ov; bi = oi; }
      }
      if (lane == 0) {
        unsigned ub = tf_bits32(KU.a, KU.b, (unsigned)row);
        float u = __uint_as_float((ub >> 9) | 0x3f800000u) - 1.0f;
        A.out[row] = ((float)bi + u) * (1.0f / 128.0f);
      }
    }
  }
}

// ---------------- launcher ----------------
extern "C" void kernel_launch(void* const* d_in, const int* in_sizes, int n_in,
                              void* d_out, int out_size, void* d_ws,
                              size_t ws_size, hipStream_t stream) {
  (void)in_sizes; (void)n_in; (void)out_size;
  const float* flow = (const float*)d_in[0];
  const float* Wsh  = (const float*)d_in[1];
  const float* bsh  = (const float*)d_in[2];
  const float* Wk   = (const float*)d_in[3];
  const float* bk   = (const float*)d_in[4];
  const float* Wv   = (const float*)d_in[5];
  const float* bv   = (const float*)d_in[6];
  const float* ln1g = (const float*)d_in[7];
  const float* ln1b = (const float*)d_in[8];
  const float* W1   = (const float*)d_in[9];
  const float* b1   = (const float*)d_in[10];
  const float* W2   = (const float*)d_in[11];
  const float* b2   = (const float*)d_in[12];
  const float* W3   = (const float*)d_in[13];
  const float* b3   = (const float*)d_in[14];
  const float* ln2g = (const float*)d_in[15];
  const float* ln2b = (const float*)d_in[16];
  const float* Wd   = (const float*)d_in[17];
  const float* bd   = (const float*)d_in[18];

  // mega3 needs versioned buffers: att x6, ah/al x6, h1/h2 x4  (~99.2 MB)
  const size_t NEED_MEGA = 99200000ull;
  const bool big = ws_size >= NEED_MEGA;
  const int vATT = big ? 6 : 1, vAH = big ? 6 : 1, vH = big ? 4 : 1;

  float* ws = (float*)d_ws;
  float* kv     = ws;                          // 2,097,152 f32
  float* attB   = kv + ROWS * KVN;             // vATT x 262,144
  float* logits = attB + vATT * ATT_STR;       // 65,536
  float* kvb    = logits + ROWS * R;           // 4,608
  int*   cnt    = (int*)(kvb + 4608);          // 1024 elections + 64 barriers
  float* P      = kvb + 4608 + 1088;           // 4,194,304 (8*512*1024)
  _Float16* hp = (_Float16*)(P + 4194304);
  _Float16* flow_h = hp;            hp += 262144;
  _Float16* flow_l = hp;            hp += 262144;
  _Float16* BKV_h  = hp;            hp += 4608 * 512;
  _Float16* BKV_l  = hp;            hp += 4608 * 512;
  _Float16* W1_h   = hp;            hp += 2097152;
  _Float16* W1_l   = hp;            hp += 2097152;
  _Float16* W2_h   = hp;            hp += 4194304;
  _Float16* W2_l   = hp;            hp += 4194304;
  _Float16* W3_h   = hp;            hp += 2097152;
  _Float16* W3_l   = hp;            hp += 2097152;
  _Float16* Wd_h   = hp;            hp += 65536;
  _Float16* Wd_l   = hp;            hp += 65536;
  _Float16* ahB    = hp;            hp += (size_t)vAH * AH_STR;
  _Float16* alB    = hp;            hp += (size_t)vAH * AH_STR;
  _Float16* h1hB   = hp;            hp += (size_t)vH * H1_STR;
  _Float16* h1lB   = hp;            hp += (size_t)vH * H1_STR;
  _Float16* h2hB   = hp;            hp += (size_t)vH * H1_STR;
  _Float16* h2lB   = hp;            hp += (size_t)vH * H1_STR;

  // ---- P0: merged prep + weight transpose/split + counter/barrier zero ----
  WArgs wa;
  wa.s[0] = Wsh; wa.h[0] = BKV_h + 4096 * 512; wa.l[0] = BKV_l + 4096 * 512;
  wa.s[1] = Wk;  wa.h[1] = BKV_h;              wa.l[1] = BKV_l;
  wa.s[2] = Wv;  wa.h[2] = BKV_h + 2048 * 512; wa.l[2] = BKV_l + 2048 * 512;
  wa.s[3] = W1;  wa.h[3] = W1_h;  wa.l[3] = W1_l;
  wa.s[4] = W2;  wa.h[4] = W2_h;  wa.l[4] = W2_l;
  wa.s[5] = W3;  wa.h[5] = W3_h;  wa.l[5] = W3_l;
  wa.s[6] = Wd;  wa.h[6] = Wd_h;  wa.l[6] = Wd_l;
  prep_split<<<2916, 256, 0, stream>>>(wa, flow, bk, bv, bsh, flow_h, flow_l,
                                       kvb, cnt);

  hipError_t ce = hipErrorUnknown;
  if (big) {
    M3 A;
    A.attB = attB; A.kv = kv; A.P = P; A.logits = logits;
    A.out = (float*)d_out;
    A.kvb = kvb; A.b1 = b1; A.b2 = b2; A.b3 = b3;
    A.ln1g = ln1g; A.ln1b = ln1b; A.ln2g = ln2g; A.ln2b = ln2b; A.bd = bd;
    A.flow_h = flow_h; A.flow_l = flow_l; A.BKV_h = BKV_h; A.BKV_l = BKV_l;
    A.W1_h = W1_h; A.W1_l = W1_l; A.W2_h = W2_h; A.W2_l = W2_l;
    A.W3_h = W3_h; A.W3_l = W3_l; A.Wd_h = Wd_h; A.Wd_l = Wd_l;
    A.ahB = ahB; A.alB = alB;
    A.h1hB = h1hB; A.h1lB = h1lB; A.h2hB = h2hB; A.h2lB = h2lB;
    A.cnt = cnt; A.bar = cnt + 1024;
    void* kargs[] = {&A};
    ce = hipLaunchCooperativeKernel(reinterpret_cast<void*>(mega3),
                                    dim3(512), dim3(256), kargs, 0, stream);
  }

  if (ce != hipSuccess) {
    // -------- fallback: verified R0 sequence (~419 us), version-0 ptrs -----
    float* att = attB;
    _Float16* att_h = ahB;
    _Float16* att_l = alB;
    _Float16* h1_h = h1hB;
    _Float16* h1_l = h1lB;
    _Float16* h2_h = h2hB;
    _Float16* h2_l = h2lB;
    gemm_kv<<<dim3(72, 8), 256, 0, stream>>>(flow_h, flow_l, BKV_h, BKV_l,
                                             kvb, kv, att);
    attn_kernel<<<ROWS, 256, 0, stream>>>(att, att_h, att_l, kv, ln1g, ln1b,
                                          0);
    for (int l = 0; l < L; l++) {
      gemm_sp<<<dim3(16, 8, 4), 256, 0, stream>>>(
          att_h, att_l, W1_h + (size_t)l * 524288, W1_l + (size_t)l * 524288,
          P, 512, 128, M);
      epi_h<<<dim3(4, ROWS), 256, 0, stream>>>(P, b1 + l * M, h1_h, h1_l, M,
                                               4, 1);
      gemm_sp<<<dim3(16, 8, 8), 256, 0, stream>>>(
          h1_h, h1_l, W2_h + (size_t)l * 1048576, W2_l + (size_t)l * 1048576,
          P, 1024, 128, M);
      epi_h<<<dim3(4, ROWS), 256, 0, stream>>>(P, b2 + l * M, h2_h, h2_l, M,
                                               8, 1);
      gemm_sp<<<dim3(8, 8, 8), 256, 0, stream>>>(
          h2_h, h2_l, W3_h + (size_t)l * 524288, W3_l + (size_t)l * 524288, P,
          1024, 128, HD);
      const int nl = (l + 1 < L) ? (l + 1) : -1;
      epi_ln_attn<<<ROWS, 256, 0, stream>>>(
          att, att_h, att_l, P, b3 + l * HD, ln2g + l * HD, ln2b + l * HD, kv,
          ln1g + (nl < 0 ? 0 : nl) * HD, ln1b + (nl < 0 ? 0 : nl) * HD, nl,
          8);
    }
    gemm_dist<<<dim3(2, 8), 256, 0, stream>>>(att_h, att_l, Wd_h, Wd_l, bd,
                                              logits);
    sample_kernel<<<SROWS / 4, 256, 0, stream>>>(logits, (float*)d_out);
  }
}